// Round 10
// baseline (426.271 us; speedup 1.0000x reference)
//
#include <hip/hip_runtime.h>
#include <hip/hip_bf16.h>
#include <cstdint>

#define NWIN   1024
#define NTOK   98
#define BIAS_N 9604   // 98*98

typedef __attribute__((ext_vector_type(8))) short bf16x8;
typedef __attribute__((ext_vector_type(4))) float f32x4;

__device__ __forceinline__ float b2f(unsigned short u) {
  union { uint32_t i; float f; } v; v.i = ((uint32_t)u) << 16; return v.f;
}
__device__ __forceinline__ float b2f_lo(uint32_t u) {
  union { uint32_t i; float f; } v; v.i = u << 16; return v.f;
}
__device__ __forceinline__ float b2f_hi(uint32_t u) {
  union { uint32_t i; float f; } v; v.i = u & 0xffff0000u; return v.f;
}
__device__ __forceinline__ unsigned short f2b(float f) {  // RNE
  union { float f; uint32_t i; } v; v.f = f;
  uint32_t r = v.i + 0x7fffu + ((v.i >> 16) & 1u);
  return (unsigned short)(r >> 16);
}
__device__ __forceinline__ float ldf(const void* p, size_t i, int f32) {
  return f32 ? ((const float*)p)[i] : b2f(((const unsigned short*)p)[i]);
}
__device__ __forceinline__ float2 ldf2(const void* p, size_t i, int f32) {  // i even
  if (f32) { const float* q = (const float*)p + i; return make_float2(q[0], q[1]); }
  uint32_t u = *(const uint32_t*)((const unsigned short*)p + i);
  return make_float2(b2f_lo(u), b2f_hi(u));
}
// per-wave f32-storage detect over x's first 64 dwords (all waves identical)
__device__ __forceinline__ int detect_f32(const uint32_t* __restrict__ xw, int lane) {
  uint32_t w = xw[lane];
  int e = (w >> 23) & 0xFF;
  unsigned long long m = __ballot(e >= 112 && e <= 134);
  return __popcll(m) >= 32;
}
// gelu via A&S 7.1.26 erf (max abs err 1.5e-7; branch-free, hw rcp+exp)
__device__ __forceinline__ float gelu_f(float x) {
  float a = fabsf(x) * 0.70710678118654752f;
  float t = __builtin_amdgcn_rcpf(1.0f + 0.3275911f * a);
  float p = ((((1.061405429f * t - 1.453152027f) * t + 1.421413741f) * t
              - 0.284496736f) * t + 0.254829592f) * t;
  float erfp = 1.0f - p * __expf(-a * a);
  return 0.5f * x * (1.0f + copysignf(erfp, x));
}

// ws offsets (bytes)
#define QG_OFF   0            // bf16 [1024][4][98][32] Q (written+read by fused kernel)
#define KG_OFF   25690112    // bf16 [1024][4][98][32] K
#define VGT_OFF  51380224    // bf16 [1024][4][32][112] transposed V
#define ZPAD_OFF 80740352    // 8192 B zeros (guards V-frag over-reads at region end)
#define BIAS_OFF 80748544    // f32, 153664 B
#define WQ_OFF   80902208    // bf16 [384][128]
#define WP_OFF   81000512    // bf16 [128][128]
#define W1_OFF   81033280    // bf16 [512][128]
#define W2_OFF   81164352    // bf16 [128][512]
#define PAR_OFF  81295424    // f32 x 1664
#define FLAG_OFF 81302080    // unused
#define LNG_OFF  81302144    // bf16 [100352][128] LN2'd tokens (written by fused K4)
// param layout (float idx)
#define P_LN1G 0
#define P_LN1B 128
#define P_LN2G 256
#define P_LN2B 384
#define P_QKVB 512
#define P_PROJB 896
#define P_B1  1024
#define P_B2  1536

// ---------------- K1: weights + params + zpad + bias table, detect inlined --------------
__global__ __launch_bounds__(256) void prep_kernel(
    const uint32_t* __restrict__ xw,
    const void* __restrict__ qkvw, const void* __restrict__ projw,
    const void* __restrict__ w1, const void* __restrict__ w2,
    const void* __restrict__ ln1g, const void* __restrict__ ln1b,
    const void* __restrict__ ln2g, const void* __restrict__ ln2b,
    const void* __restrict__ qkvb, const void* __restrict__ projb,
    const void* __restrict__ b1, const void* __restrict__ b2,
    const int* __restrict__ rel_idx, const void* __restrict__ tbl,
    unsigned short* __restrict__ wq_t, unsigned short* __restrict__ wp_t,
    unsigned short* __restrict__ w1_t, unsigned short* __restrict__ w2_t,
    float* __restrict__ par, unsigned short* __restrict__ zpad,
    float* __restrict__ bias) {
  const int f32 = detect_f32(xw, threadIdx.x & 63);
  const int bid = blockIdx.x;
  if (bid < 791) {
    int idx = bid * 256 + threadIdx.x;
    if (idx < 49152) {
      int n = idx >> 7, k = idx & 127;
      wq_t[idx] = f2b(ldf(qkvw, (size_t)k * 384 + n, f32));
    } else if ((idx -= 49152) < 16384) {
      int n = idx >> 7, k = idx & 127;
      wp_t[idx] = f2b(ldf(projw, (size_t)k * 128 + n, f32));
    } else if ((idx -= 16384) < 65536) {
      int n = idx >> 7, k = idx & 127;
      w1_t[idx] = f2b(ldf(w1, (size_t)k * 512 + n, f32));
    } else if ((idx -= 65536) < 65536) {
      int n = idx >> 9, k = idx & 511;
      w2_t[idx] = f2b(ldf(w2, (size_t)k * 128 + n, f32));
    } else if ((idx -= 65536) < 1664) {
      float v;
      if      (idx < 128)  v = ldf(ln1g, idx, f32);
      else if (idx < 256)  v = ldf(ln1b, idx - 128, f32);
      else if (idx < 384)  v = ldf(ln2g, idx - 256, f32);
      else if (idx < 512)  v = ldf(ln2b, idx - 384, f32);
      else if (idx < 896)  v = ldf(qkvb, idx - 512, f32);
      else if (idx < 1024) v = ldf(projb, idx - 896, f32);
      else if (idx < 1536) v = ldf(b1, idx - 1024, f32);
      else                 v = ldf(b2, idx - 1536, f32);
      par[idx] = v;
    } else if ((idx -= 1664) < 4096) {
      zpad[idx] = 0;
    }
  } else {
    int i = (bid - 791) * 256 + threadIdx.x;
    if (i < 4 * BIAS_N) {
      int h = i / BIAS_N, ij = i % BIAS_N;
      bias[i] = ldf(tbl, (size_t)rel_idx[ij] * 4 + h, f32);
    }
  }
}

// ---------------- K4: FUSED LN1+QKV+attention+proj+residual+LN2, 1 block/window ----------
// r10: vs r9 — Q moved from LDS to global qg (same producer/consumer path as K).
// Phase-B LDS peak drops to lnx alone; kernel LDS peak = olds 30464 B => 5 blocks/CU,
// entire 1024-block grid co-resident (capacity 1280). Extends the measured r8->r9
// occupancy-beats-traffic trend (+1 blk/CU > intermediate-traffic cost).
// Overlays: A/B: lnx[98][136] @0. C: plh[4][16][132] @0. post: olds[112][136] @0;
//           then pout[56][132] f32 @0.
__global__ __launch_bounds__(256, 5) void attn_fused_kernel(
    const void* __restrict__ x,
    const unsigned short* __restrict__ wq_t, const float* __restrict__ bias,
    const unsigned short* __restrict__ wp_t, const float* __restrict__ par,
    unsigned short* __restrict__ qg, unsigned short* __restrict__ kg,
    unsigned short* __restrict__ vgt, unsigned short* __restrict__ lng,
    void* __restrict__ out) {
  __shared__ __align__(16) unsigned short smem[15232];   // 30464 B
  const int f32 = detect_f32((const uint32_t*)x, threadIdx.x & 63);
  const int tid = threadIdx.x, wave = tid >> 6, lane = tid & 63;
  const int quad = lane >> 4, lcol = lane & 15;
  const int win = blockIdx.x, h = wave;
  const int bb = win >> 8, rW = win & 255;
  const int wd = rW >> 6, r2 = rW & 63, wh = r2 >> 3, ww = r2 & 7;

  unsigned short* lnx = smem;            // [98][136]

  // ---- Phase A: LN1 + gather -> lnx ----
  for (int t = wave; t < NTOK; t += 4) {
    int td = t / 49, r3 = t % 49, th = r3 / 7, tw = r3 % 7;
    int sd = (wd * 2 + td + 1) & 7;
    int sh = (wh * 7 + th + 3) % 56;
    int sw = (ww * 7 + tw + 3) % 56;
    size_t src = ((((size_t)bb * 8 + sd) * 56 + sh) * 56 + sw) * 128;
    int c0 = lane * 2;
    float2 f = ldf2(x, src + c0, f32);
    float s = f.x + f.y, ss = f.x * f.x + f.y * f.y;
#pragma unroll
    for (int off = 32; off >= 1; off >>= 1) { s += __shfl_xor(s, off); ss += __shfl_xor(ss, off); }
    float mu = s * (1.0f / 128.0f);
    float var = ss * (1.0f / 128.0f) - mu * mu;
    float rs = rsqrtf(var + 1e-5f);
    float y0 = (f.x - mu) * rs * par[P_LN1G + c0] + par[P_LN1B + c0];
    float y1 = (f.y - mu) * rs * par[P_LN1G + c0 + 1] + par[P_LN1B + c0 + 1];
    *(uint32_t*)(lnx + t * 136 + c0) = (uint32_t)f2b(y0) | ((uint32_t)f2b(y1) << 16);
  }
  __syncthreads();

  // ---- Phase B: QKV MFMA. Q -> qg, K -> kg, V -> vgt (all global, L2-hot) ----
  for (int p = 0; p < 6; ++p) {
    const int n = p * 64 + wave * 16 + lcol;
    bf16x8 bfr[4];
#pragma unroll
    for (int ks4 = 0; ks4 < 4; ++ks4)
      bfr[ks4] = *(const bf16x8*)(wq_t + (size_t)n * 128 + ks4 * 32 + quad * 8);
    const int region = p >> 1;                      // 0=Q 1=K 2=V
    const int head = (p & 1) * 2 + (wave >> 1);     // uniform per (p,wave)
    const int d = (wave & 1) * 16 + lcol;
    const float bc = par[P_QKVB + n];
    if (region < 2) {
      unsigned short* dstg = (region == 0 ? qg : kg) +
                             ((size_t)win * 4 + head) * 3136 + d;
      const float scale = region == 0 ? 0.17677669529663687f : 1.0f;
      for (int mt = 0; mt < 7; ++mt) {
        f32x4 acc = (f32x4){0.f, 0.f, 0.f, 0.f};
#pragma unroll
        for (int ks4 = 0; ks4 < 4; ++ks4) {
          bf16x8 a = *(const bf16x8*)(lnx + min(mt * 16 + lcol, NTOK - 1) * 136 +
                                      ks4 * 32 + quad * 8);
          acc = __builtin_amdgcn_mfma_f32_16x16x32_bf16(a, bfr[ks4], acc, 0, 0, 0);
        }
#pragma unroll
        for (int rr = 0; rr < 4; ++rr) {
          int m = mt * 16 + quad * 4 + rr;
          if (m < NTOK) dstg[m * 32] = f2b((acc[rr] + bc) * scale);
        }
      }
    } else {
      unsigned short* dstv = vgt + (((size_t)win * 4 + head) * 32 + d) * 112;
      for (int mt = 0; mt < 7; ++mt) {
        f32x4 acc = (f32x4){0.f, 0.f, 0.f, 0.f};
#pragma unroll
        for (int ks4 = 0; ks4 < 4; ++ks4) {
          bf16x8 a = *(const bf16x8*)(lnx + min(mt * 16 + lcol, NTOK - 1) * 136 +
                                      ks4 * 32 + quad * 8);
          acc = __builtin_amdgcn_mfma_f32_16x16x32_bf16(a, bfr[ks4], acc, 0, 0, 0);
        }
        ushort4 w;
        int m0 = mt * 16 + quad * 4;
        w.x = (m0 + 0 < NTOK) ? f2b(acc[0] + bc) : (unsigned short)0;
        w.y = (m0 + 1 < NTOK) ? f2b(acc[1] + bc) : (unsigned short)0;
        w.z = (m0 + 2 < NTOK) ? f2b(acc[2] + bc) : (unsigned short)0;
        w.w = (m0 + 3 < NTOK) ? f2b(acc[3] + bc) : (unsigned short)0;
        *(ushort4*)(dstv + m0) = w;
      }
    }
  }
  __syncthreads();   // qg/kg/vgt complete; lnx dead (plh overlays)

  // ---- Phase C: attention for head h = wave ----
  const size_t hb = ((size_t)win * 4 + h) * 3136;
  const unsigned short* vbase = vgt + (((size_t)win * 4 + h) * 32) * 112;
  unsigned short* plh = smem + h * 2112;   // [16][132], overlays lnx

  bf16x8 aq[7], bk[7];
#pragma unroll
  for (int t = 0; t < 7; ++t) {
    int row = min(t * 16 + lcol, NTOK - 1);
    aq[t] = *(const bf16x8*)(qg + hb + (size_t)row * 32 + quad * 8);
    bk[t] = *(const bf16x8*)(kg + hb + (size_t)row * 32 + quad * 8);
  }
  for (int idx = lane; idx < 16 * 16; idx += 64) {
    int rr = idx >> 4, c = 112 + (idx & 15);
    plh[rr * 132 + c] = 0;
  }

  const float* bh = bias + h * BIAS_N;
  f32x4 o[7][2];
  for (int mt = 0; mt < 7; ++mt) {
    f32x4 s[7];
#pragma unroll
    for (int nt = 0; nt < 7; ++nt)
      s[nt] = __builtin_amdgcn_mfma_f32_16x16x32_bf16(aq[mt], bk[nt],
                                                      (f32x4){0.f, 0.f, 0.f, 0.f}, 0, 0, 0);
    const int ib = mt * 16 + quad * 4;
#pragma unroll
    for (int nt = 0; nt < 7; ++nt) {
      int j = nt * 16 + lcol;
      bool jv = j < NTOK;
#pragma unroll
      for (int r = 0; r < 4; ++r) {
        int ic = min(ib + r, NTOK - 1);
        s[nt][r] = jv ? (s[nt][r] + bh[ic * NTOK + j]) : -3.0e38f;
      }
    }
    float mx[4], sum[4], inv[4];
#pragma unroll
    for (int r = 0; r < 4; ++r) {
      float m = s[0][r];
#pragma unroll
      for (int nt = 1; nt < 7; ++nt) m = fmaxf(m, s[nt][r]);
      mx[r] = m;
    }
#pragma unroll
    for (int off = 1; off < 16; off <<= 1)
#pragma unroll
      for (int r = 0; r < 4; ++r) mx[r] = fmaxf(mx[r], __shfl_xor(mx[r], off));
#pragma unroll
    for (int r = 0; r < 4; ++r) sum[r] = 0.f;
#pragma unroll
    for (int nt = 0; nt < 7; ++nt)
#pragma unroll
      for (int r = 0; r < 4; ++r) {
        float e = __expf(s[nt][r] - mx[r]);
        s[nt][r] = e; sum[r] += e;
      }
#pragma unroll
    for (int off = 1; off < 16; off <<= 1)
#pragma unroll
      for (int r = 0; r < 4; ++r) sum[r] += __shfl_xor(sum[r], off);
#pragma unroll
    for (int r = 0; r < 4; ++r) inv[r] = 1.0f / sum[r];
#pragma unroll
    for (int nt = 0; nt < 7; ++nt)
#pragma unroll
      for (int r = 0; r < 4; ++r)
        plh[(quad * 4 + r) * 132 + nt * 16 + lcol] = f2b(s[nt][r] * inv[r]);
    // PV: A = P tile (K padded), B = V^T frags (vgt, L2-hot)
#pragma unroll
    for (int n2 = 0; n2 < 2; ++n2) {
      f32x4 acc = (f32x4){0.f, 0.f, 0.f, 0.f};
#pragma unroll
      for (int kp = 0; kp < 4; ++kp) {
        bf16x8 a = *(const bf16x8*)(plh + lcol * 132 + kp * 32 + quad * 8);
        bf16x8 b = *(const bf16x8*)(vbase + (size_t)(n2 * 16 + lcol) * 112 +
                                    kp * 32 + quad * 8);
        acc = __builtin_amdgcn_mfma_f32_16x16x32_bf16(a, b, acc, 0, 0, 0);
      }
      o[mt][n2] = acc;
    }
  }
  __syncthreads();   // plh dead before olds overlays smem

  // ---- attn-out -> olds[112][136] @0 ----
  unsigned short* olds = smem;
#pragma unroll
  for (int mt = 0; mt < 7; ++mt)
#pragma unroll
    for (int n2 = 0; n2 < 2; ++n2)
#pragma unroll
      for (int r = 0; r < 4; ++r)
        olds[(mt * 16 + quad * 4 + r) * 136 + h * 32 + n2 * 16 + lcol] = f2b(o[mt][n2][r]);
  __syncthreads();

  // ---- proj into registers ----
  f32x4 pr[2][7];
  for (int t2 = 0; t2 < 2; ++t2) {
    const int n = (h * 2 + t2) * 16 + lcol;
    bf16x8 bw[4];
#pragma unroll
    for (int kp = 0; kp < 4; ++kp)
      bw[kp] = *(const bf16x8*)(wp_t + (size_t)n * 128 + kp * 32 + quad * 8);
    for (int mt = 0; mt < 7; ++mt) {
      f32x4 acc = (f32x4){0.f, 0.f, 0.f, 0.f};
#pragma unroll
      for (int kp = 0; kp < 4; ++kp) {
        bf16x8 a = *(const bf16x8*)(olds + (mt * 16 + lcol) * 136 + kp * 32 + quad * 8);
        acc = __builtin_amdgcn_mfma_f32_16x16x32_bf16(a, bw[kp], acc, 0, 0, 0);
      }
      pr[t2][mt] = acc;
    }
  }
  __syncthreads();   // olds dead before pout overlays smem

  // ---- two-pass epilogue: pout[56][132] f32, residual + LN2 + stores ----
  const int c = (tid & 31) * 4;
  const float4 gv = *(const float4*)(par + P_LN2G + c);
  const float4 bv = *(const float4*)(par + P_LN2B + c);
  float* pout = (float*)smem;
  for (int pass = 0; pass < 2; ++pass) {
    const int mlo = pass * 56;
    for (int t2 = 0; t2 < 2; ++t2) {
      const int n = (h * 2 + t2) * 16 + lcol;
      const float bc = par[P_PROJB + n];
#pragma unroll
      for (int mt = 0; mt < 7; ++mt)
#pragma unroll
        for (int r = 0; r < 4; ++r) {
          int m = mt * 16 + quad * 4 + r;
          if (m >= mlo && m < mlo + 56 && m < NTOK)
            pout[(m - mlo) * 132 + n] = pr[t2][mt][r] + bc;
        }
    }
    __syncthreads();
    for (int i = tid >> 5; i < 56; i += 8) {
      int m = mlo + i;
      if (m >= NTOK) break;
      int td = m / 49, r3 = m % 49, th = r3 / 7, tw = r3 % 7;
      int sd = (wd * 2 + td + 1) & 7;
      int sh = (wh * 7 + th + 3) % 56;
      int sw = (ww * 7 + tw + 3) % 56;
      size_t base = ((((size_t)bb * 8 + sd) * 56 + sh) * 56 + sw) * 128 + c;
      float4 p = *(const float4*)(pout + i * 132 + c);
      float4 v;
      if (f32) {
        const float4 xr = *(const float4*)((const float*)x + base);
        v = make_float4(p.x + xr.x, p.y + xr.y, p.z + xr.z, p.w + xr.w);
        *(float4*)((float*)out + base) = v;
      } else {
        const ushort4 xr = *(const ushort4*)((const unsigned short*)x + base);
        v = make_float4(p.x + b2f(xr.x), p.y + b2f(xr.y),
                        p.z + b2f(xr.z), p.w + b2f(xr.w));
        ushort4 ov;
        ov.x = f2b(v.x); ov.y = f2b(v.y); ov.z = f2b(v.z); ov.w = f2b(v.w);
        *(ushort4*)((unsigned short*)out + base) = ov;
      }
      // fused LN2 over the 32-lane row -> lng (bf16)
      float s = v.x + v.y + v.z + v.w;
      float ss = v.x * v.x + v.y * v.y + v.z * v.z + v.w * v.w;
#pragma unroll
      for (int off = 1; off < 32; off <<= 1) {
        s += __shfl_xor(s, off); ss += __shfl_xor(ss, off);
      }
      float mu = s * (1.0f / 128.0f);
      float var = ss * (1.0f / 128.0f) - mu * mu;
      float rs = rsqrtf(var + 1e-5f);
      ushort4 lv;
      lv.x = f2b((v.x - mu) * rs * gv.x + bv.x);
      lv.y = f2b((v.y - mu) * rs * gv.y + bv.y);
      lv.z = f2b((v.z - mu) * rs * gv.z + bv.z);
      lv.w = f2b((v.w - mu) * rs * gv.w + bv.w);
      *(ushort4*)(lng + base) = lv;
    }
    if (pass == 0) __syncthreads();   // pout reused by pass 1
  }
}

// ---------------- K5: MLP1(gelu) + MLP2 + residual (LN2 pre-computed in K4) ----------------
__global__ __launch_bounds__(256) void mlp_kernel(
    const unsigned short* __restrict__ w1_t, const unsigned short* __restrict__ w2_t,
    const float* __restrict__ par, const void* __restrict__ x,
    const unsigned short* __restrict__ lng, void* __restrict__ out) {
  __shared__ __align__(16) unsigned short hbuf[32 * 264];  // 16896 B; pout overlays
  const int f32 = detect_f32((const uint32_t*)x, threadIdx.x & 63);
  const int tid = threadIdx.x, wave = tid >> 6, lane = tid & 63;
  const int quad = lane >> 4, lcol = lane & 15;
  const int m0 = blockIdx.x * 32;
  const int nb = wave * 16 + lcol;

  // A-frags (LN2'd token rows) direct from lng; invariant across the K loop
  bf16x8 a1[2][4];
#pragma unroll
  for (int mt = 0; mt < 2; ++mt)
#pragma unroll
    for (int ks = 0; ks < 4; ++ks)
      a1[mt][ks] = *(const bf16x8*)(lng + (size_t)(m0 + mt * 16 + lcol) * 128 +
                                    ks * 32 + quad * 8);

  f32x4 acc2[2][2];
#pragma unroll
  for (int a = 0; a < 2; ++a)
#pragma unroll
    for (int b = 0; b < 2; ++b) acc2[a][b] = (f32x4){0.f, 0.f, 0.f, 0.f};

#pragma unroll 1
  for (int g = 0; g < 2; ++g) {
    for (int p = 0; p < 4; ++p) {
      const int nl = p * 64 + nb;
      const int n = g * 256 + nl;
      bf16x8 bfr[4];
#pragma unroll
      for (int ks = 0; ks < 4; ++ks)
        bfr[ks] = *(const bf16x8*)(w1_t + (size_t)n * 128 + ks * 32 + quad * 8);
      const float bc = par[P_B1 + n];
#pragma unroll
      for (int mt = 0; mt < 2; ++mt) {
        f32x4 acc = (f32x4){0.f, 0.f, 0.f, 0.f};
#pragma unroll
        for (int ks = 0; ks < 4; ++ks)
          acc = __builtin_amdgcn_mfma_f32_16x16x32_bf16(a1[mt][ks], bfr[ks], acc, 0, 0, 0);
#pragma unroll
        for (int rr = 0; rr < 4; ++rr) {
          int m = mt * 16 + quad * 4 + rr;
          hbuf[m * 264 + nl] = f2b(gelu_f(acc[rr] + bc));
        }
      }
    }
    __syncthreads();

#pragma unroll
    for (int np = 0; np < 2; ++np) {
      for (int kp = 0; kp < 2; ++kp) {
        bf16x8 b2r[4];
#pragma unroll
        for (int ks = 0; ks < 4; ++ks)
          b2r[ks] = *(const bf16x8*)(w2_t + (size_t)(np * 64 + nb) * 512 + g * 256 +
                                     kp * 128 + ks * 32 + quad * 8);
#pragma unroll
        for (int mt = 0; mt < 2; ++mt) {
#pragma unroll
          for (int ks = 0; ks < 4; ++ks) {
            bf16x8 a = *(const bf16x8*)(hbuf + (mt * 16 + lcol) * 264 + kp * 128 +
                                        ks * 32 + quad * 8);
            acc2[np][mt] = __builtin_amdgcn_mfma_f32_16x16x32_bf16(a, b2r[ks], acc2[np][mt], 0, 0, 0);
          }
        }
      }
    }
    __syncthreads();
  }

  float* pout = (float*)hbuf;
#pragma unroll
  for (int np = 0; np < 2; ++np) {
    const int n = np * 64 + nb;
    const float bc = par[P_B2 + n];
#pragma unroll
    for (int mt = 0; mt < 2; ++mt)
#pragma unroll
      for (int rr = 0; rr < 4; ++rr)
        pout[(mt * 16 + quad * 4 + rr) * 132 + n] = acc2[np][mt][rr] + bc;
  }
  __syncthreads();

  for (int i = tid; i < 1024; i += 256) {
    int t = i >> 5, c = (i & 31) * 4;
    size_t base = (size_t)(m0 + t) * 128 + c;
    float4 p = *(const float4*)(pout + t * 132 + c);
    if (f32) {
      const float4 xr = *(const float4*)((const float*)out + base);
      float4 ov = make_float4(p.x + xr.x, p.y + xr.y, p.z + xr.z, p.w + xr.w);
      *(float4*)((float*)out + base) = ov;
    } else {
      const ushort4 xr = *(const ushort4*)((const unsigned short*)out + base);
      ushort4 ov;
      ov.x = f2b(p.x + b2f(xr.x)); ov.y = f2b(p.y + b2f(xr.y));
      ov.z = f2b(p.z + b2f(xr.z)); ov.w = f2b(p.w + b2f(xr.w));
      *(ushort4*)((unsigned short*)out + base) = ov;
    }
  }
}

// ---------------- host launch ----------------
extern "C" void kernel_launch(void* const* d_in, const int* in_sizes, int n_in,
                              void* d_out, int out_size, void* d_ws, size_t ws_size,
                              hipStream_t stream) {
  const void* x      = d_in[0];
  const int*  rel    = (const int*)d_in[1];
  const void* rpb    = d_in[2];
  const void* qkv_w  = d_in[3];
  const void* qkv_b  = d_in[4];
  const void* proj_w = d_in[5];
  const void* proj_b = d_in[6];
  const void* ln1_g  = d_in[7];
  const void* ln1_b  = d_in[8];
  const void* ln2_g  = d_in[9];
  const void* ln2_b  = d_in[10];
  const void* w1     = d_in[11];
  const void* b1     = d_in[12];
  const void* w2     = d_in[13];
  const void* b2     = d_in[14];

  char* ws = (char*)d_ws;
  unsigned short* qg   = (unsigned short*)(ws + QG_OFF);
  unsigned short* kg   = (unsigned short*)(ws + KG_OFF);
  unsigned short* vgt  = (unsigned short*)(ws + VGT_OFF);
  unsigned short* zpad = (unsigned short*)(ws + ZPAD_OFF);
  float*          bias = (float*)(ws + BIAS_OFF);
  unsigned short* wq_t = (unsigned short*)(ws + WQ_OFF);
  unsigned short* wp_t = (unsigned short*)(ws + WP_OFF);
  unsigned short* w1_t = (unsigned short*)(ws + W1_OFF);
  unsigned short* w2_t = (unsigned short*)(ws + W2_OFF);
  float*          par  = (float*)(ws + PAR_OFF);
  unsigned short* lng  = (unsigned short*)(ws + LNG_OFF);

  prep_kernel<<<791 + 151, 256, 0, stream>>>(
      (const uint32_t*)x, qkv_w, proj_w, w1, w2, ln1_g, ln1_b, ln2_g, ln2_b,
      qkv_b, proj_b, b1, b2, rel, rpb,
      wq_t, wp_t, w1_t, w2_t, par, zpad, bias);
  attn_fused_kernel<<<NWIN, 256, 0, stream>>>(x, wq_t, bias, wp_t, par,
                                              qg, kg, vgt, lng, d_out);
  mlp_kernel<<<100352 / 32, 256, 0, stream>>>(w1_t, w2_t, par, x, lng, d_out);
}

// Round 11
// 364.001 us; speedup vs baseline: 1.1711x; 1.1711x over previous
//
#include <hip/hip_runtime.h>
#include <hip/hip_bf16.h>
#include <cstdint>

#define NWIN   1024
#define NTOK   98
#define BIAS_N 9604   // 98*98

typedef __attribute__((ext_vector_type(8))) short bf16x8;
typedef __attribute__((ext_vector_type(4))) float f32x4;

__device__ __forceinline__ float b2f(unsigned short u) {
  union { uint32_t i; float f; } v; v.i = ((uint32_t)u) << 16; return v.f;
}
__device__ __forceinline__ float b2f_lo(uint32_t u) {
  union { uint32_t i; float f; } v; v.i = u << 16; return v.f;
}
__device__ __forceinline__ float b2f_hi(uint32_t u) {
  union { uint32_t i; float f; } v; v.i = u & 0xffff0000u; return v.f;
}
__device__ __forceinline__ unsigned short f2b(float f) {  // RNE
  union { float f; uint32_t i; } v; v.f = f;
  uint32_t r = v.i + 0x7fffu + ((v.i >> 16) & 1u);
  return (unsigned short)(r >> 16);
}
__device__ __forceinline__ float ldf(const void* p, size_t i, int f32) {
  return f32 ? ((const float*)p)[i] : b2f(((const unsigned short*)p)[i]);
}
__device__ __forceinline__ float2 ldf2(const void* p, size_t i, int f32) {  // i even
  if (f32) { const float* q = (const float*)p + i; return make_float2(q[0], q[1]); }
  uint32_t u = *(const uint32_t*)((const unsigned short*)p + i);
  return make_float2(b2f_lo(u), b2f_hi(u));
}
// per-wave f32-storage detect over x's first 64 dwords (all waves identical)
__device__ __forceinline__ int detect_f32(const uint32_t* __restrict__ xw, int lane) {
  uint32_t w = xw[lane];
  int e = (w >> 23) & 0xFF;
  unsigned long long m = __ballot(e >= 112 && e <= 134);
  return __popcll(m) >= 32;
}
// gelu via A&S 7.1.26 erf (max abs err 1.5e-7; branch-free, hw rcp+exp)
__device__ __forceinline__ float gelu_f(float x) {
  float a = fabsf(x) * 0.70710678118654752f;
  float t = __builtin_amdgcn_rcpf(1.0f + 0.3275911f * a);
  float p = ((((1.061405429f * t - 1.453152027f) * t + 1.421413741f) * t
              - 0.284496736f) * t + 0.254829592f) * t;
  float erfp = 1.0f - p * __expf(-a * a);
  return 0.5f * x * (1.0f + copysignf(erfp, x));
}

// ws offsets (bytes) — QG region dead space
#define QG_OFF   0
#define KG_OFF   25690112    // bf16 [1024][4][98][32] K (written+read by fused kernel)
#define VGT_OFF  51380224    // bf16 [1024][4][32][112] transposed V
#define ZPAD_OFF 80740352    // 8192 B zeros (guards V-frag over-reads at region end)
#define BIAS_OFF 80748544    // f32, 153664 B
#define WQ_OFF   80902208    // bf16 [384][128]
#define WP_OFF   81000512    // bf16 [128][128]
#define W1_OFF   81033280    // bf16 [512][128]
#define W2_OFF   81164352    // bf16 [128][512]
#define PAR_OFF  81295424    // f32 x 1664
#define FLAG_OFF 81302080    // unused
#define LNG_OFF  81302144    // bf16 [100352][128] LN2'd tokens (written by fused K4)
// param layout (float idx)
#define P_LN1G 0
#define P_LN1B 128
#define P_LN2G 256
#define P_LN2B 384
#define P_QKVB 512
#define P_PROJB 896
#define P_B1  1024
#define P_B2  1536

// ---------------- K1: weights + params + zpad + bias table, detect inlined --------------
__global__ __launch_bounds__(256) void prep_kernel(
    const uint32_t* __restrict__ xw,
    const void* __restrict__ qkvw, const void* __restrict__ projw,
    const void* __restrict__ w1, const void* __restrict__ w2,
    const void* __restrict__ ln1g, const void* __restrict__ ln1b,
    const void* __restrict__ ln2g, const void* __restrict__ ln2b,
    const void* __restrict__ qkvb, const void* __restrict__ projb,
    const void* __restrict__ b1, const void* __restrict__ b2,
    const int* __restrict__ rel_idx, const void* __restrict__ tbl,
    unsigned short* __restrict__ wq_t, unsigned short* __restrict__ wp_t,
    unsigned short* __restrict__ w1_t, unsigned short* __restrict__ w2_t,
    float* __restrict__ par, unsigned short* __restrict__ zpad,
    float* __restrict__ bias) {
  const int f32 = detect_f32(xw, threadIdx.x & 63);
  const int bid = blockIdx.x;
  if (bid < 791) {
    int idx = bid * 256 + threadIdx.x;
    if (idx < 49152) {
      int n = idx >> 7, k = idx & 127;
      wq_t[idx] = f2b(ldf(qkvw, (size_t)k * 384 + n, f32));
    } else if ((idx -= 49152) < 16384) {
      int n = idx >> 7, k = idx & 127;
      wp_t[idx] = f2b(ldf(projw, (size_t)k * 128 + n, f32));
    } else if ((idx -= 16384) < 65536) {
      int n = idx >> 7, k = idx & 127;
      w1_t[idx] = f2b(ldf(w1, (size_t)k * 512 + n, f32));
    } else if ((idx -= 65536) < 65536) {
      int n = idx >> 9, k = idx & 511;
      w2_t[idx] = f2b(ldf(w2, (size_t)k * 128 + n, f32));
    } else if ((idx -= 65536) < 1664) {
      float v;
      if      (idx < 128)  v = ldf(ln1g, idx, f32);
      else if (idx < 256)  v = ldf(ln1b, idx - 128, f32);
      else if (idx < 384)  v = ldf(ln2g, idx - 256, f32);
      else if (idx < 512)  v = ldf(ln2b, idx - 384, f32);
      else if (idx < 896)  v = ldf(qkvb, idx - 512, f32);
      else if (idx < 1024) v = ldf(projb, idx - 896, f32);
      else if (idx < 1536) v = ldf(b1, idx - 1024, f32);
      else                 v = ldf(b2, idx - 1536, f32);
      par[idx] = v;
    } else if ((idx -= 1664) < 4096) {
      zpad[idx] = 0;
    }
  } else {
    int i = (bid - 791) * 256 + threadIdx.x;
    if (i < 4 * BIAS_N) {
      int h = i / BIAS_N, ij = i % BIAS_N;
      bias[i] = ldf(tbl, (size_t)rel_idx[ij] * 4 + h, f32);
    }
  }
}

// ---------------- K4: FUSED LN1+QKV+attention+proj+residual+LN2, 1 block/window ----------
// r11: reverted to r9's exact structure (Q in LDS qs, K/V global, 3 blocks/CU).
// r10's Q-to-global at 5 blocks/CU thrashed L2 (per-XCD live intermediates 12.6MB > 4MB):
// FETCH 123->314MB, dur 172->206. r9 sits at the measured optimum of the
// occupancy-vs-L2-capacity trade-off.
__global__ __launch_bounds__(256, 3) void attn_fused_kernel(
    const void* __restrict__ x,
    const unsigned short* __restrict__ wq_t, const float* __restrict__ bias,
    const unsigned short* __restrict__ wp_t, const float* __restrict__ par,
    unsigned short* __restrict__ kg, unsigned short* __restrict__ vgt,
    unsigned short* __restrict__ lng, void* __restrict__ out) {
  __shared__ __align__(16) unsigned short smem[25872];   // 51744 B
  const int f32 = detect_f32((const uint32_t*)x, threadIdx.x & 63);
  const int tid = threadIdx.x, wave = tid >> 6, lane = tid & 63;
  const int quad = lane >> 4, lcol = lane & 15;
  const int win = blockIdx.x, h = wave;
  const int bb = win >> 8, rW = win & 255;
  const int wd = rW >> 6, r2 = rW & 63, wh = r2 >> 3, ww = r2 & 7;

  unsigned short* lnx = smem;            // [98][136]
  unsigned short* qs  = smem + 13328;    // [4][98][32]

  // ---- Phase A: LN1 + gather -> lnx ----
  for (int t = wave; t < NTOK; t += 4) {
    int td = t / 49, r3 = t % 49, th = r3 / 7, tw = r3 % 7;
    int sd = (wd * 2 + td + 1) & 7;
    int sh = (wh * 7 + th + 3) % 56;
    int sw = (ww * 7 + tw + 3) % 56;
    size_t src = ((((size_t)bb * 8 + sd) * 56 + sh) * 56 + sw) * 128;
    int c0 = lane * 2;
    float2 f = ldf2(x, src + c0, f32);
    float s = f.x + f.y, ss = f.x * f.x + f.y * f.y;
#pragma unroll
    for (int off = 32; off >= 1; off >>= 1) { s += __shfl_xor(s, off); ss += __shfl_xor(ss, off); }
    float mu = s * (1.0f / 128.0f);
    float var = ss * (1.0f / 128.0f) - mu * mu;
    float rs = rsqrtf(var + 1e-5f);
    float y0 = (f.x - mu) * rs * par[P_LN1G + c0] + par[P_LN1B + c0];
    float y1 = (f.y - mu) * rs * par[P_LN1G + c0 + 1] + par[P_LN1B + c0 + 1];
    *(uint32_t*)(lnx + t * 136 + c0) = (uint32_t)f2b(y0) | ((uint32_t)f2b(y1) << 16);
  }
  __syncthreads();

  // ---- Phase B: QKV MFMA. Q -> qs (LDS), K -> kg (global), V -> vgt (global) ----
  for (int p = 0; p < 6; ++p) {
    const int n = p * 64 + wave * 16 + lcol;
    bf16x8 bfr[4];
#pragma unroll
    for (int ks4 = 0; ks4 < 4; ++ks4)
      bfr[ks4] = *(const bf16x8*)(wq_t + (size_t)n * 128 + ks4 * 32 + quad * 8);
    const int region = p >> 1;                      // 0=Q 1=K 2=V
    const int head = (p & 1) * 2 + (wave >> 1);     // uniform per (p,wave)
    const int d = (wave & 1) * 16 + lcol;
    const float bc = par[P_QKVB + n];
    if (region == 0) {
      unsigned short* dstl = qs + head * 3136 + d;
      for (int mt = 0; mt < 7; ++mt) {
        f32x4 acc = (f32x4){0.f, 0.f, 0.f, 0.f};
#pragma unroll
        for (int ks4 = 0; ks4 < 4; ++ks4) {
          bf16x8 a = *(const bf16x8*)(lnx + min(mt * 16 + lcol, NTOK - 1) * 136 +
                                      ks4 * 32 + quad * 8);
          acc = __builtin_amdgcn_mfma_f32_16x16x32_bf16(a, bfr[ks4], acc, 0, 0, 0);
        }
#pragma unroll
        for (int rr = 0; rr < 4; ++rr) {
          int m = mt * 16 + quad * 4 + rr;
          if (m < NTOK) dstl[m * 32] = f2b((acc[rr] + bc) * 0.17677669529663687f);
        }
      }
    } else if (region == 1) {
      unsigned short* dstg = kg + ((size_t)win * 4 + head) * 3136 + d;
      for (int mt = 0; mt < 7; ++mt) {
        f32x4 acc = (f32x4){0.f, 0.f, 0.f, 0.f};
#pragma unroll
        for (int ks4 = 0; ks4 < 4; ++ks4) {
          bf16x8 a = *(const bf16x8*)(lnx + min(mt * 16 + lcol, NTOK - 1) * 136 +
                                      ks4 * 32 + quad * 8);
          acc = __builtin_amdgcn_mfma_f32_16x16x32_bf16(a, bfr[ks4], acc, 0, 0, 0);
        }
#pragma unroll
        for (int rr = 0; rr < 4; ++rr) {
          int m = mt * 16 + quad * 4 + rr;
          if (m < NTOK) dstg[m * 32] = f2b(acc[rr] + bc);
        }
      }
    } else {
      unsigned short* dstv = vgt + (((size_t)win * 4 + head) * 32 + d) * 112;
      for (int mt = 0; mt < 7; ++mt) {
        f32x4 acc = (f32x4){0.f, 0.f, 0.f, 0.f};
#pragma unroll
        for (int ks4 = 0; ks4 < 4; ++ks4) {
          bf16x8 a = *(const bf16x8*)(lnx + min(mt * 16 + lcol, NTOK - 1) * 136 +
                                      ks4 * 32 + quad * 8);
          acc = __builtin_amdgcn_mfma_f32_16x16x32_bf16(a, bfr[ks4], acc, 0, 0, 0);
        }
        ushort4 w;
        int m0 = mt * 16 + quad * 4;
        w.x = (m0 + 0 < NTOK) ? f2b(acc[0] + bc) : (unsigned short)0;
        w.y = (m0 + 1 < NTOK) ? f2b(acc[1] + bc) : (unsigned short)0;
        w.z = (m0 + 2 < NTOK) ? f2b(acc[2] + bc) : (unsigned short)0;
        w.w = (m0 + 3 < NTOK) ? f2b(acc[3] + bc) : (unsigned short)0;
        *(ushort4*)(dstv + m0) = w;
      }
    }
  }
  __syncthreads();   // qs/kg/vgt complete; lnx dead (plh overlays)

  // ---- Phase C: attention for head h = wave ----
  const size_t hb = ((size_t)win * 4 + h) * 3136;
  const unsigned short* vbase = vgt + (((size_t)win * 4 + h) * 32) * 112;
  unsigned short* plh = smem + h * 2112;   // [16][132], overlays lnx

  bf16x8 aq[7], bk[7];
#pragma unroll
  for (int t = 0; t < 7; ++t) {
    int row = min(t * 16 + lcol, NTOK - 1);
    aq[t] = *(const bf16x8*)(qs + h * 3136 + row * 32 + quad * 8);
    bk[t] = *(const bf16x8*)(kg + hb + (size_t)row * 32 + quad * 8);
  }
  for (int idx = lane; idx < 16 * 16; idx += 64) {
    int rr = idx >> 4, c = 112 + (idx & 15);
    plh[rr * 132 + c] = 0;
  }

  const float* bh = bias + h * BIAS_N;
  f32x4 o[7][2];
  for (int mt = 0; mt < 7; ++mt) {
    f32x4 s[7];
#pragma unroll
    for (int nt = 0; nt < 7; ++nt)
      s[nt] = __builtin_amdgcn_mfma_f32_16x16x32_bf16(aq[mt], bk[nt],
                                                      (f32x4){0.f, 0.f, 0.f, 0.f}, 0, 0, 0);
    const int ib = mt * 16 + quad * 4;
#pragma unroll
    for (int nt = 0; nt < 7; ++nt) {
      int j = nt * 16 + lcol;
      bool jv = j < NTOK;
#pragma unroll
      for (int r = 0; r < 4; ++r) {
        int ic = min(ib + r, NTOK - 1);
        s[nt][r] = jv ? (s[nt][r] + bh[ic * NTOK + j]) : -3.0e38f;
      }
    }
    float mx[4], sum[4], inv[4];
#pragma unroll
    for (int r = 0; r < 4; ++r) {
      float m = s[0][r];
#pragma unroll
      for (int nt = 1; nt < 7; ++nt) m = fmaxf(m, s[nt][r]);
      mx[r] = m;
    }
#pragma unroll
    for (int off = 1; off < 16; off <<= 1)
#pragma unroll
      for (int r = 0; r < 4; ++r) mx[r] = fmaxf(mx[r], __shfl_xor(mx[r], off));
#pragma unroll
    for (int r = 0; r < 4; ++r) sum[r] = 0.f;
#pragma unroll
    for (int nt = 0; nt < 7; ++nt)
#pragma unroll
      for (int r = 0; r < 4; ++r) {
        float e = __expf(s[nt][r] - mx[r]);
        s[nt][r] = e; sum[r] += e;
      }
#pragma unroll
    for (int off = 1; off < 16; off <<= 1)
#pragma unroll
      for (int r = 0; r < 4; ++r) sum[r] += __shfl_xor(sum[r], off);
#pragma unroll
    for (int r = 0; r < 4; ++r) inv[r] = 1.0f / sum[r];
#pragma unroll
    for (int nt = 0; nt < 7; ++nt)
#pragma unroll
      for (int r = 0; r < 4; ++r)
        plh[(quad * 4 + r) * 132 + nt * 16 + lcol] = f2b(s[nt][r] * inv[r]);
    // PV: A = P tile (K padded), B = V^T frags (vgt, L2-hot)
#pragma unroll
    for (int n2 = 0; n2 < 2; ++n2) {
      f32x4 acc = (f32x4){0.f, 0.f, 0.f, 0.f};
#pragma unroll
      for (int kp = 0; kp < 4; ++kp) {
        bf16x8 a = *(const bf16x8*)(plh + lcol * 132 + kp * 32 + quad * 8);
        bf16x8 b = *(const bf16x8*)(vbase + (size_t)(n2 * 16 + lcol) * 112 +
                                    kp * 32 + quad * 8);
        acc = __builtin_amdgcn_mfma_f32_16x16x32_bf16(a, b, acc, 0, 0, 0);
      }
      o[mt][n2] = acc;
    }
  }
  __syncthreads();   // plh/qs dead before olds overlays smem

  // ---- attn-out -> olds[112][136] @0 ----
  unsigned short* olds = smem;
#pragma unroll
  for (int mt = 0; mt < 7; ++mt)
#pragma unroll
    for (int n2 = 0; n2 < 2; ++n2)
#pragma unroll
      for (int r = 0; r < 4; ++r)
        olds[(mt * 16 + quad * 4 + r) * 136 + h * 32 + n2 * 16 + lcol] = f2b(o[mt][n2][r]);
  __syncthreads();

  // ---- proj into registers ----
  f32x4 pr[2][7];
  for (int t2 = 0; t2 < 2; ++t2) {
    const int n = (h * 2 + t2) * 16 + lcol;
    bf16x8 bw[4];
#pragma unroll
    for (int kp = 0; kp < 4; ++kp)
      bw[kp] = *(const bf16x8*)(wp_t + (size_t)n * 128 + kp * 32 + quad * 8);
    for (int mt = 0; mt < 7; ++mt) {
      f32x4 acc = (f32x4){0.f, 0.f, 0.f, 0.f};
#pragma unroll
      for (int kp = 0; kp < 4; ++kp) {
        bf16x8 a = *(const bf16x8*)(olds + (mt * 16 + lcol) * 136 + kp * 32 + quad * 8);
        acc = __builtin_amdgcn_mfma_f32_16x16x32_bf16(a, bw[kp], acc, 0, 0, 0);
      }
      pr[t2][mt] = acc;
    }
  }
  __syncthreads();   // olds dead before pout overlays smem

  // ---- two-pass epilogue: pout[56][132] f32, residual + LN2 + stores ----
  const int c = (tid & 31) * 4;
  const float4 gv = *(const float4*)(par + P_LN2G + c);
  const float4 bv = *(const float4*)(par + P_LN2B + c);
  float* pout = (float*)smem;
  for (int pass = 0; pass < 2; ++pass) {
    const int mlo = pass * 56;
    for (int t2 = 0; t2 < 2; ++t2) {
      const int n = (h * 2 + t2) * 16 + lcol;
      const float bc = par[P_PROJB + n];
#pragma unroll
      for (int mt = 0; mt < 7; ++mt)
#pragma unroll
        for (int r = 0; r < 4; ++r) {
          int m = mt * 16 + quad * 4 + r;
          if (m >= mlo && m < mlo + 56 && m < NTOK)
            pout[(m - mlo) * 132 + n] = pr[t2][mt][r] + bc;
        }
    }
    __syncthreads();
    for (int i = tid >> 5; i < 56; i += 8) {
      int m = mlo + i;
      if (m >= NTOK) break;
      int td = m / 49, r3 = m % 49, th = r3 / 7, tw = r3 % 7;
      int sd = (wd * 2 + td + 1) & 7;
      int sh = (wh * 7 + th + 3) % 56;
      int sw = (ww * 7 + tw + 3) % 56;
      size_t base = ((((size_t)bb * 8 + sd) * 56 + sh) * 56 + sw) * 128 + c;
      float4 p = *(const float4*)(pout + i * 132 + c);
      float4 v;
      if (f32) {
        const float4 xr = *(const float4*)((const float*)x + base);
        v = make_float4(p.x + xr.x, p.y + xr.y, p.z + xr.z, p.w + xr.w);
        *(float4*)((float*)out + base) = v;
      } else {
        const ushort4 xr = *(const ushort4*)((const unsigned short*)x + base);
        v = make_float4(p.x + b2f(xr.x), p.y + b2f(xr.y),
                        p.z + b2f(xr.z), p.w + b2f(xr.w));
        ushort4 ov;
        ov.x = f2b(v.x); ov.y = f2b(v.y); ov.z = f2b(v.z); ov.w = f2b(v.w);
        *(ushort4*)((unsigned short*)out + base) = ov;
      }
      // fused LN2 over the 32-lane row -> lng (bf16)
      float s = v.x + v.y + v.z + v.w;
      float ss = v.x * v.x + v.y * v.y + v.z * v.z + v.w * v.w;
#pragma unroll
      for (int off = 1; off < 32; off <<= 1) {
        s += __shfl_xor(s, off); ss += __shfl_xor(ss, off);
      }
      float mu = s * (1.0f / 128.0f);
      float var = ss * (1.0f / 128.0f) - mu * mu;
      float rs = rsqrtf(var + 1e-5f);
      ushort4 lv;
      lv.x = f2b((v.x - mu) * rs * gv.x + bv.x);
      lv.y = f2b((v.y - mu) * rs * gv.y + bv.y);
      lv.z = f2b((v.z - mu) * rs * gv.z + bv.z);
      lv.w = f2b((v.w - mu) * rs * gv.w + bv.w);
      *(ushort4*)(lng + base) = lv;
    }
    if (pass == 0) __syncthreads();   // pout reused by pass 1
  }
}

// ---------------- K5: MLP1(gelu) + MLP2 + residual, 64 tokens/block ----------------
// r11: tokens/block 32 -> 64. Halves the per-token w1/w2 L2 stream (822 -> 411 MB
// aggregate) and per-token barrier count. a1[4][4] + acc2[2][4] all statically
// indexed (stay in registers). hbuf[64][264] = 33792 B; pout[64][132] f32 overlays.
__global__ __launch_bounds__(256) void mlp_kernel(
    const unsigned short* __restrict__ w1_t, const unsigned short* __restrict__ w2_t,
    const float* __restrict__ par, const void* __restrict__ x,
    const unsigned short* __restrict__ lng, void* __restrict__ out) {
  __shared__ __align__(16) unsigned short hbuf[64 * 264];  // 33792 B; pout overlays
  const int f32 = detect_f32((const uint32_t*)x, threadIdx.x & 63);
  const int tid = threadIdx.x, wave = tid >> 6, lane = tid & 63;
  const int quad = lane >> 4, lcol = lane & 15;
  const int m0 = blockIdx.x * 64;
  const int nb = wave * 16 + lcol;

  // A-frags (LN2'd token rows) direct from lng; invariant across the K loop
  bf16x8 a1[4][4];
#pragma unroll
  for (int mt = 0; mt < 4; ++mt)
#pragma unroll
    for (int ks = 0; ks < 4; ++ks)
      a1[mt][ks] = *(const bf16x8*)(lng + (size_t)(m0 + mt * 16 + lcol) * 128 +
                                    ks * 32 + quad * 8);

  f32x4 acc2[2][4];
#pragma unroll
  for (int a = 0; a < 2; ++a)
#pragma unroll
    for (int b = 0; b < 4; ++b) acc2[a][b] = (f32x4){0.f, 0.f, 0.f, 0.f};

#pragma unroll 1
  for (int g = 0; g < 2; ++g) {
    // ---- GEMM1 + gelu for hidden n in [g*256, g*256+256) ----
    for (int p = 0; p < 4; ++p) {
      const int nl = p * 64 + nb;
      const int n = g * 256 + nl;
      bf16x8 bfr[4];
#pragma unroll
      for (int ks = 0; ks < 4; ++ks)
        bfr[ks] = *(const bf16x8*)(w1_t + (size_t)n * 128 + ks * 32 + quad * 8);
      const float bc = par[P_B1 + n];
#pragma unroll
      for (int mt = 0; mt < 4; ++mt) {
        f32x4 acc = (f32x4){0.f, 0.f, 0.f, 0.f};
#pragma unroll
        for (int ks = 0; ks < 4; ++ks)
          acc = __builtin_amdgcn_mfma_f32_16x16x32_bf16(a1[mt][ks], bfr[ks], acc, 0, 0, 0);
#pragma unroll
        for (int rr = 0; rr < 4; ++rr) {
          int m = mt * 16 + quad * 4 + rr;
          hbuf[m * 264 + nl] = f2b(gelu_f(acc[rr] + bc));
        }
      }
    }
    __syncthreads();   // hbuf fully written for this half

    // ---- GEMM2 partial over this K=256 half ----
#pragma unroll
    for (int np = 0; np < 2; ++np) {
      for (int kp = 0; kp < 2; ++kp) {
        bf16x8 b2r[4];
#pragma unroll
        for (int ks = 0; ks < 4; ++ks)
          b2r[ks] = *(const bf16x8*)(w2_t + (size_t)(np * 64 + nb) * 512 + g * 256 +
                                     kp * 128 + ks * 32 + quad * 8);
#pragma unroll
        for (int mt = 0; mt < 4; ++mt) {
#pragma unroll
          for (int ks = 0; ks < 4; ++ks) {
            bf16x8 a = *(const bf16x8*)(hbuf + (mt * 16 + lcol) * 264 + kp * 128 +
                                        ks * 32 + quad * 8);
            acc2[np][mt] = __builtin_amdgcn_mfma_f32_16x16x32_bf16(a, b2r[ks], acc2[np][mt], 0, 0, 0);
          }
        }
      }
    }
    __syncthreads();   // hbuf reads done before next half overwrites (or pout overlays)
  }

  // ---- stage MLP2+bias (f32) -> pout[64][132] overlaying hbuf ----
  float* pout = (float*)hbuf;
#pragma unroll
  for (int np = 0; np < 2; ++np) {
    const int n = np * 64 + nb;
    const float bc = par[P_B2 + n];
#pragma unroll
    for (int mt = 0; mt < 4; ++mt)
#pragma unroll
      for (int rr = 0; rr < 4; ++rr)
        pout[(mt * 16 + quad * 4 + rr) * 132 + n] = acc2[np][mt][rr] + bc;
  }
  __syncthreads();

  // ---- coalesced residual + store: 64 contiguous token rows (32 KB) ----
  for (int i = tid; i < 2048; i += 256) {
    int t = i >> 5, c = (i & 31) * 4;
    size_t base = (size_t)(m0 + t) * 128 + c;
    float4 p = *(const float4*)(pout + t * 132 + c);
    if (f32) {
      const float4 xr = *(const float4*)((const float*)out + base);
      float4 ov = make_float4(p.x + xr.x, p.y + xr.y, p.z + xr.z, p.w + xr.w);
      *(float4*)((float*)out + base) = ov;
    } else {
      const ushort4 xr = *(const ushort4*)((const unsigned short*)out + base);
      ushort4 ov;
      ov.x = f2b(p.x + b2f(xr.x)); ov.y = f2b(p.y + b2f(xr.y));
      ov.z = f2b(p.z + b2f(xr.z)); ov.w = f2b(p.w + b2f(xr.w));
      *(ushort4*)((unsigned short*)out + base) = ov;
    }
  }
}

// ---------------- host launch ----------------
extern "C" void kernel_launch(void* const* d_in, const int* in_sizes, int n_in,
                              void* d_out, int out_size, void* d_ws, size_t ws_size,
                              hipStream_t stream) {
  const void* x      = d_in[0];
  const int*  rel    = (const int*)d_in[1];
  const void* rpb    = d_in[2];
  const void* qkv_w  = d_in[3];
  const void* qkv_b  = d_in[4];
  const void* proj_w = d_in[5];
  const void* proj_b = d_in[6];
  const void* ln1_g  = d_in[7];
  const void* ln1_b  = d_in[8];
  const void* ln2_g  = d_in[9];
  const void* ln2_b  = d_in[10];
  const void* w1     = d_in[11];
  const void* b1     = d_in[12];
  const void* w2     = d_in[13];
  const void* b2     = d_in[14];

  char* ws = (char*)d_ws;
  unsigned short* kg   = (unsigned short*)(ws + KG_OFF);
  unsigned short* vgt  = (unsigned short*)(ws + VGT_OFF);
  unsigned short* zpad = (unsigned short*)(ws + ZPAD_OFF);
  float*          bias = (float*)(ws + BIAS_OFF);
  unsigned short* wq_t = (unsigned short*)(ws + WQ_OFF);
  unsigned short* wp_t = (unsigned short*)(ws + WP_OFF);
  unsigned short* w1_t = (unsigned short*)(ws + W1_OFF);
  unsigned short* w2_t = (unsigned short*)(ws + W2_OFF);
  float*          par  = (float*)(ws + PAR_OFF);
  unsigned short* lng  = (unsigned short*)(ws + LNG_OFF);

  prep_kernel<<<791 + 151, 256, 0, stream>>>(
      (const uint32_t*)x, qkv_w, proj_w, w1, w2, ln1_g, ln1_b, ln2_g, ln2_b,
      qkv_b, proj_b, b1, b2, rel, rpb,
      wq_t, wp_t, w1_t, w2_t, par, zpad, bias);
  attn_fused_kernel<<<NWIN, 256, 0, stream>>>(x, wq_t, bias, wp_t, par,
                                              kg, vgt, lng, d_out);
  mlp_kernel<<<100352 / 64, 256, 0, stream>>>(w1_t, w2_t, par, x, lng, d_out);
}

// Round 12
// 363.347 us; speedup vs baseline: 1.1732x; 1.0018x over previous
//
#include <hip/hip_runtime.h>
#include <hip/hip_bf16.h>
#include <cstdint>

#define NWIN   1024
#define NTOK   98
#define BIAS_N 9604   // 98*98

typedef __attribute__((ext_vector_type(8))) short bf16x8;
typedef __attribute__((ext_vector_type(4))) float f32x4;

__device__ __forceinline__ float b2f(unsigned short u) {
  union { uint32_t i; float f; } v; v.i = ((uint32_t)u) << 16; return v.f;
}
__device__ __forceinline__ float b2f_lo(uint32_t u) {
  union { uint32_t i; float f; } v; v.i = u << 16; return v.f;
}
__device__ __forceinline__ float b2f_hi(uint32_t u) {
  union { uint32_t i; float f; } v; v.i = u & 0xffff0000u; return v.f;
}
__device__ __forceinline__ unsigned short f2b(float f) {  // RNE
  union { float f; uint32_t i; } v; v.f = f;
  uint32_t r = v.i + 0x7fffu + ((v.i >> 16) & 1u);
  return (unsigned short)(r >> 16);
}
__device__ __forceinline__ float ldf(const void* p, size_t i, int f32) {
  return f32 ? ((const float*)p)[i] : b2f(((const unsigned short*)p)[i]);
}
__device__ __forceinline__ float2 ldf2(const void* p, size_t i, int f32) {  // i even
  if (f32) { const float* q = (const float*)p + i; return make_float2(q[0], q[1]); }
  uint32_t u = *(const uint32_t*)((const unsigned short*)p + i);
  return make_float2(b2f_lo(u), b2f_hi(u));
}
// per-wave f32-storage detect over x's first 64 dwords (all waves identical)
__device__ __forceinline__ int detect_f32(const uint32_t* __restrict__ xw, int lane) {
  uint32_t w = xw[lane];
  int e = (w >> 23) & 0xFF;
  unsigned long long m = __ballot(e >= 112 && e <= 134);
  return __popcll(m) >= 32;
}
// gelu via A&S 7.1.26 erf (max abs err 1.5e-7; branch-free, hw rcp+exp)
__device__ __forceinline__ float gelu_f(float x) {
  float a = fabsf(x) * 0.70710678118654752f;
  float t = __builtin_amdgcn_rcpf(1.0f + 0.3275911f * a);
  float p = ((((1.061405429f * t - 1.453152027f) * t + 1.421413741f) * t
              - 0.284496736f) * t + 0.254829592f) * t;
  float erfp = 1.0f - p * __expf(-a * a);
  return 0.5f * x * (1.0f + copysignf(erfp, x));
}

// ws offsets (bytes)
#define BIAST_OFF 0          // f32 [4][112][112] transposed bias (in dead QG region)
#define KG_OFF   25690112    // bf16 [1024][4][98][32] K (written+read by fused kernel)
#define VGT_OFF  51380224    // bf16 [1024][4][32][112] transposed V
#define ZPAD_OFF 80740352    // 8192 B zeros (guards V-frag over-reads at region end)
#define WQ_OFF   80902208    // bf16 [384][128]
#define WP_OFF   81000512    // bf16 [128][128]
#define W1_OFF   81033280    // bf16 [512][128]
#define W2_OFF   81164352    // bf16 [128][512]
#define PAR_OFF  81295424    // f32 x 1664
#define LNG_OFF  81302144    // bf16 [100352][128] LN2'd tokens (written by fused K4)
// param layout (float idx)
#define P_LN1G 0
#define P_LN1B 128
#define P_LN2G 256
#define P_LN2B 384
#define P_QKVB 512
#define P_PROJB 896
#define P_B1  1024
#define P_B2  1536

// ---------------- K1: weights + params + zpad + transposed bias, detect inlined ---------
__global__ __launch_bounds__(256) void prep_kernel(
    const uint32_t* __restrict__ xw,
    const void* __restrict__ qkvw, const void* __restrict__ projw,
    const void* __restrict__ w1, const void* __restrict__ w2,
    const void* __restrict__ ln1g, const void* __restrict__ ln1b,
    const void* __restrict__ ln2g, const void* __restrict__ ln2b,
    const void* __restrict__ qkvb, const void* __restrict__ projb,
    const void* __restrict__ b1, const void* __restrict__ b2,
    const int* __restrict__ rel_idx, const void* __restrict__ tbl,
    unsigned short* __restrict__ wq_t, unsigned short* __restrict__ wp_t,
    unsigned short* __restrict__ w1_t, unsigned short* __restrict__ w2_t,
    float* __restrict__ par, unsigned short* __restrict__ zpad,
    float* __restrict__ bias_t) {
  const int f32 = detect_f32(xw, threadIdx.x & 63);
  const int bid = blockIdx.x;
  if (bid < 791) {
    int idx = bid * 256 + threadIdx.x;
    if (idx < 49152) {
      int n = idx >> 7, k = idx & 127;
      wq_t[idx] = f2b(ldf(qkvw, (size_t)k * 384 + n, f32));
    } else if ((idx -= 49152) < 16384) {
      int n = idx >> 7, k = idx & 127;
      wp_t[idx] = f2b(ldf(projw, (size_t)k * 128 + n, f32));
    } else if ((idx -= 16384) < 65536) {
      int n = idx >> 7, k = idx & 127;
      w1_t[idx] = f2b(ldf(w1, (size_t)k * 512 + n, f32));
    } else if ((idx -= 65536) < 65536) {
      int n = idx >> 9, k = idx & 511;
      w2_t[idx] = f2b(ldf(w2, (size_t)k * 128 + n, f32));
    } else if ((idx -= 65536) < 1664) {
      float v;
      if      (idx < 128)  v = ldf(ln1g, idx, f32);
      else if (idx < 256)  v = ldf(ln1b, idx - 128, f32);
      else if (idx < 384)  v = ldf(ln2g, idx - 256, f32);
      else if (idx < 512)  v = ldf(ln2b, idx - 384, f32);
      else if (idx < 896)  v = ldf(qkvb, idx - 512, f32);
      else if (idx < 1024) v = ldf(projb, idx - 896, f32);
      else if (idx < 1536) v = ldf(b1, idx - 1024, f32);
      else                 v = ldf(b2, idx - 1536, f32);
      par[idx] = v;
    } else if ((idx -= 1664) < 4096) {
      zpad[idx] = 0;
    }
  } else {
    // bias_t[h][j][i] (i is fast dim, padded to 112) = tbl[rel_idx[i*98+j]][h]
    int t = (bid - 791) * 256 + threadIdx.x;
    if (t < 4 * 112 * 112) {
      int h = t / 12544, rem = t % 12544, j = rem / 112, i = rem % 112;
      float v = 0.f;
      if (i < NTOK && j < NTOK) v = ldf(tbl, (size_t)rel_idx[i * NTOK + j] * 4 + h, f32);
      bias_t[t] = v;
    }
  }
}

// ---------------- K4: FUSED LN1+QKV+attention+proj+residual+LN2, 1 block/window ----------
// r12 changes vs r11:
// (a) Phase-B remap: wave w computes Q/K/V exclusively for head w
//     (n = region*128 + w*32 + (p&1)*16 + lcol) -> qs/kg/vgt strictly wave-private
//     -> B->C barrier DELETED; B+C run wave-independent (skew hides mem stalls).
//     Same-wave kg/vgt store->load ordered by explicit s_waitcnt vmcnt(0) at C entry.
// (b) plh overlays the wave's OWN dead qs slice (aq consumed into regs first).
// (c) bias pre-transposed [h][j][112] -> 49 float4 loads/wave (was 196 dwords),
//     row-clamp VALU removed (pad rows read zeros; outputs discarded).
__global__ __launch_bounds__(256, 3) void attn_fused_kernel(
    const void* __restrict__ x,
    const unsigned short* __restrict__ wq_t, const float* __restrict__ bias_t,
    const unsigned short* __restrict__ wp_t, const float* __restrict__ par,
    unsigned short* __restrict__ kg, unsigned short* __restrict__ vgt,
    unsigned short* __restrict__ lng, void* __restrict__ out) {
  __shared__ __align__(16) unsigned short smem[25872];   // 51744 B
  const int f32 = detect_f32((const uint32_t*)x, threadIdx.x & 63);
  const int tid = threadIdx.x, wave = tid >> 6, lane = tid & 63;
  const int quad = lane >> 4, lcol = lane & 15;
  const int win = blockIdx.x, h = wave;
  const int bb = win >> 8, rW = win & 255;
  const int wd = rW >> 6, r2 = rW & 63, wh = r2 >> 3, ww = r2 & 7;

  unsigned short* lnx = smem;            // [98][136]
  unsigned short* qs  = smem + 13328;    // [4][98][32] wave-private slices

  // ---- Phase A: LN1 + gather -> lnx ----
  for (int t = wave; t < NTOK; t += 4) {
    int td = t / 49, r3 = t % 49, th = r3 / 7, tw = r3 % 7;
    int sd = (wd * 2 + td + 1) & 7;
    int sh = (wh * 7 + th + 3) % 56;
    int sw = (ww * 7 + tw + 3) % 56;
    size_t src = ((((size_t)bb * 8 + sd) * 56 + sh) * 56 + sw) * 128;
    int c0 = lane * 2;
    float2 f = ldf2(x, src + c0, f32);
    float s = f.x + f.y, ss = f.x * f.x + f.y * f.y;
#pragma unroll
    for (int off = 32; off >= 1; off >>= 1) { s += __shfl_xor(s, off); ss += __shfl_xor(ss, off); }
    float mu = s * (1.0f / 128.0f);
    float var = ss * (1.0f / 128.0f) - mu * mu;
    float rs = rsqrtf(var + 1e-5f);
    float y0 = (f.x - mu) * rs * par[P_LN1G + c0] + par[P_LN1B + c0];
    float y1 = (f.y - mu) * rs * par[P_LN1G + c0 + 1] + par[P_LN1B + c0 + 1];
    *(uint32_t*)(lnx + t * 136 + c0) = (uint32_t)f2b(y0) | ((uint32_t)f2b(y1) << 16);
  }
  __syncthreads();   // lnx complete (read by all waves in B)

  // ---- Phase B: QKV MFMA, head h = wave (wave-private outputs) ----
  for (int p = 0; p < 6; ++p) {
    const int region = p >> 1;                      // 0=Q 1=K 2=V
    const int d = (p & 1) * 16 + lcol;              // d in [0,32)
    const int n = region * 128 + h * 32 + d;
    bf16x8 bfr[4];
#pragma unroll
    for (int ks4 = 0; ks4 < 4; ++ks4)
      bfr[ks4] = *(const bf16x8*)(wq_t + (size_t)n * 128 + ks4 * 32 + quad * 8);
    const float bc = par[P_QKVB + n];
    if (region == 0) {
      unsigned short* dstl = qs + h * 3136 + d;
      for (int mt = 0; mt < 7; ++mt) {
        f32x4 acc = (f32x4){0.f, 0.f, 0.f, 0.f};
#pragma unroll
        for (int ks4 = 0; ks4 < 4; ++ks4) {
          bf16x8 a = *(const bf16x8*)(lnx + min(mt * 16 + lcol, NTOK - 1) * 136 +
                                      ks4 * 32 + quad * 8);
          acc = __builtin_amdgcn_mfma_f32_16x16x32_bf16(a, bfr[ks4], acc, 0, 0, 0);
        }
#pragma unroll
        for (int rr = 0; rr < 4; ++rr) {
          int m = mt * 16 + quad * 4 + rr;
          if (m < NTOK) dstl[m * 32] = f2b((acc[rr] + bc) * 0.17677669529663687f);
        }
      }
    } else if (region == 1) {
      unsigned short* dstg = kg + ((size_t)win * 4 + h) * 3136 + d;
      for (int mt = 0; mt < 7; ++mt) {
        f32x4 acc = (f32x4){0.f, 0.f, 0.f, 0.f};
#pragma unroll
        for (int ks4 = 0; ks4 < 4; ++ks4) {
          bf16x8 a = *(const bf16x8*)(lnx + min(mt * 16 + lcol, NTOK - 1) * 136 +
                                      ks4 * 32 + quad * 8);
          acc = __builtin_amdgcn_mfma_f32_16x16x32_bf16(a, bfr[ks4], acc, 0, 0, 0);
        }
#pragma unroll
        for (int rr = 0; rr < 4; ++rr) {
          int m = mt * 16 + quad * 4 + rr;
          if (m < NTOK) dstg[m * 32] = f2b(acc[rr] + bc);
        }
      }
    } else {
      unsigned short* dstv = vgt + (((size_t)win * 4 + h) * 32 + d) * 112;
      for (int mt = 0; mt < 7; ++mt) {
        f32x4 acc = (f32x4){0.f, 0.f, 0.f, 0.f};
#pragma unroll
        for (int ks4 = 0; ks4 < 4; ++ks4) {
          bf16x8 a = *(const bf16x8*)(lnx + min(mt * 16 + lcol, NTOK - 1) * 136 +
                                      ks4 * 32 + quad * 8);
          acc = __builtin_amdgcn_mfma_f32_16x16x32_bf16(a, bfr[ks4], acc, 0, 0, 0);
        }
        ushort4 w;
        int m0 = mt * 16 + quad * 4;
        w.x = (m0 + 0 < NTOK) ? f2b(acc[0] + bc) : (unsigned short)0;
        w.y = (m0 + 1 < NTOK) ? f2b(acc[1] + bc) : (unsigned short)0;
        w.z = (m0 + 2 < NTOK) ? f2b(acc[2] + bc) : (unsigned short)0;
        w.w = (m0 + 3 < NTOK) ? f2b(acc[3] + bc) : (unsigned short)0;
        *(ushort4*)(dstv + m0) = w;
      }
    }
  }
  // NO barrier: qs/kg/vgt are wave-private. Drain own global stores before C reads.
  asm volatile("s_waitcnt vmcnt(0)" ::: "memory");

  // ---- Phase C: attention for head h = wave ----
  const size_t hb = ((size_t)win * 4 + h) * 3136;
  const unsigned short* vbase = vgt + (((size_t)win * 4 + h) * 32) * 112;

  // consume own qs into regs, then overlay plh onto own qs slice (in-wave ds order)
  bf16x8 aq[7], bk[7];
#pragma unroll
  for (int t = 0; t < 7; ++t) {
    int row = min(t * 16 + lcol, NTOK - 1);
    aq[t] = *(const bf16x8*)(qs + h * 3136 + row * 32 + quad * 8);
    bk[t] = *(const bf16x8*)(kg + hb + (size_t)row * 32 + quad * 8);
  }
  unsigned short* plh = qs + h * 3136;   // [16][132] overlays own dead qs slice
  for (int idx = lane; idx < 16 * 16; idx += 64) {
    int rr = idx >> 4, c = 112 + (idx & 15);
    plh[rr * 132 + c] = 0;
  }

  const float* bh = bias_t + h * 12544;   // [112][112], [j][i]
  f32x4 o[7][2];
  for (int mt = 0; mt < 7; ++mt) {
    f32x4 s[7];
#pragma unroll
    for (int nt = 0; nt < 7; ++nt)
      s[nt] = __builtin_amdgcn_mfma_f32_16x16x32_bf16(aq[mt], bk[nt],
                                                      (f32x4){0.f, 0.f, 0.f, 0.f}, 0, 0, 0);
    const int ib = mt * 16 + quad * 4;
#pragma unroll
    for (int nt = 0; nt < 7; ++nt) {
      int j = nt * 16 + lcol;
      bool jv = j < NTOK;
      const float4 bv4 = *(const float4*)(bh + j * 112 + ib);
      s[nt][0] = jv ? (s[nt][0] + bv4.x) : -3.0e38f;
      s[nt][1] = jv ? (s[nt][1] + bv4.y) : -3.0e38f;
      s[nt][2] = jv ? (s[nt][2] + bv4.z) : -3.0e38f;
      s[nt][3] = jv ? (s[nt][3] + bv4.w) : -3.0e38f;
    }
    float mx[4], sum[4], inv[4];
#pragma unroll
    for (int r = 0; r < 4; ++r) {
      float m = s[0][r];
#pragma unroll
      for (int nt = 1; nt < 7; ++nt) m = fmaxf(m, s[nt][r]);
      mx[r] = m;
    }
#pragma unroll
    for (int off = 1; off < 16; off <<= 1)
#pragma unroll
      for (int r = 0; r < 4; ++r) mx[r] = fmaxf(mx[r], __shfl_xor(mx[r], off));
#pragma unroll
    for (int r = 0; r < 4; ++r) sum[r] = 0.f;
#pragma unroll
    for (int nt = 0; nt < 7; ++nt)
#pragma unroll
      for (int r = 0; r < 4; ++r) {
        float e = __expf(s[nt][r] - mx[r]);
        s[nt][r] = e; sum[r] += e;
      }
#pragma unroll
    for (int off = 1; off < 16; off <<= 1)
#pragma unroll
      for (int r = 0; r < 4; ++r) sum[r] += __shfl_xor(sum[r], off);
#pragma unroll
    for (int r = 0; r < 4; ++r) inv[r] = 1.0f / sum[r];
#pragma unroll
    for (int nt = 0; nt < 7; ++nt)
#pragma unroll
      for (int r = 0; r < 4; ++r)
        plh[(quad * 4 + r) * 132 + nt * 16 + lcol] = f2b(s[nt][r] * inv[r]);
    // PV: A = P tile (K padded), B = V^T frags (vgt, L2-hot, same-wave produced)
#pragma unroll
    for (int n2 = 0; n2 < 2; ++n2) {
      f32x4 acc = (f32x4){0.f, 0.f, 0.f, 0.f};
#pragma unroll
      for (int kp = 0; kp < 4; ++kp) {
        bf16x8 a = *(const bf16x8*)(plh + lcol * 132 + kp * 32 + quad * 8);
        bf16x8 b = *(const bf16x8*)(vbase + (size_t)(n2 * 16 + lcol) * 112 +
                                    kp * 32 + quad * 8);
        acc = __builtin_amdgcn_mfma_f32_16x16x32_bf16(a, b, acc, 0, 0, 0);
      }
      o[mt][n2] = acc;
    }
  }
  __syncthreads();   // ALL waves done with B (lnx reads) + C (plh) before olds overlay

  // ---- attn-out -> olds[112][136] @0 ----
  unsigned short* olds = smem;
#pragma unroll
  for (int mt = 0; mt < 7; ++mt)
#pragma unroll
    for (int n2 = 0; n2 < 2; ++n2)
#pragma unroll
      for (int r = 0; r < 4; ++r)
        olds[(mt * 16 + quad * 4 + r) * 136 + h * 32 + n2 * 16 + lcol] = f2b(o[mt][n2][r]);
  __syncthreads();

  // ---- proj into registers ----
  f32x4 pr[2][7];
  for (int t2 = 0; t2 < 2; ++t2) {
    const int n = (h * 2 + t2) * 16 + lcol;
    bf16x8 bw[4];
#pragma unroll
    for (int kp = 0; kp < 4; ++kp)
      bw[kp] = *(const bf16x8*)(wp_t + (size_t)n * 128 + kp * 32 + quad * 8);
    for (int mt = 0; mt < 7; ++mt) {
      f32x4 acc = (f32x4){0.f, 0.f, 0.f, 0.f};
#pragma unroll
      for (int kp = 0; kp < 4; ++kp) {
        bf16x8 a = *(const bf16x8*)(olds + (mt * 16 + lcol) * 136 + kp * 32 + quad * 8);
        acc = __builtin_amdgcn_mfma_f32_16x16x32_bf16(a, bw[kp], acc, 0, 0, 0);
      }
      pr[t2][mt] = acc;
    }
  }
  __syncthreads();   // olds dead before pout overlays smem

  // ---- two-pass epilogue: pout[56][132] f32, residual + LN2 + stores ----
  const int c = (tid & 31) * 4;
  const float4 gv = *(const float4*)(par + P_LN2G + c);
  const float4 bv = *(const float4*)(par + P_LN2B + c);
  float* pout = (float*)smem;
  for (int pass = 0; pass < 2; ++pass) {
    const int mlo = pass * 56;
    for (int t2 = 0; t2 < 2; ++t2) {
      const int n = (h * 2 + t2) * 16 + lcol;
      const float bc = par[P_PROJB + n];
#pragma unroll
      for (int mt = 0; mt < 7; ++mt)
#pragma unroll
        for (int r = 0; r < 4; ++r) {
          int m = mt * 16 + quad * 4 + r;
          if (m >= mlo && m < mlo + 56 && m < NTOK)
            pout[(m - mlo) * 132 + n] = pr[t2][mt][r] + bc;
        }
    }
    __syncthreads();
    for (int i = tid >> 5; i < 56; i += 8) {
      int m = mlo + i;
      if (m >= NTOK) break;
      int td = m / 49, r3 = m % 49, th = r3 / 7, tw = r3 % 7;
      int sd = (wd * 2 + td + 1) & 7;
      int sh = (wh * 7 + th + 3) % 56;
      int sw = (ww * 7 + tw + 3) % 56;
      size_t base = ((((size_t)bb * 8 + sd) * 56 + sh) * 56 + sw) * 128 + c;
      float4 p = *(const float4*)(pout + i * 132 + c);
      float4 v;
      if (f32) {
        const float4 xr = *(const float4*)((const float*)x + base);
        v = make_float4(p.x + xr.x, p.y + xr.y, p.z + xr.z, p.w + xr.w);
        *(float4*)((float*)out + base) = v;
      } else {
        const ushort4 xr = *(const ushort4*)((const unsigned short*)x + base);
        v = make_float4(p.x + b2f(xr.x), p.y + b2f(xr.y),
                        p.z + b2f(xr.z), p.w + b2f(xr.w));
        ushort4 ov;
        ov.x = f2b(v.x); ov.y = f2b(v.y); ov.z = f2b(v.z); ov.w = f2b(v.w);
        *(ushort4*)((unsigned short*)out + base) = ov;
      }
      // fused LN2 over the 32-lane row -> lng (bf16)
      float s = v.x + v.y + v.z + v.w;
      float ss = v.x * v.x + v.y * v.y + v.z * v.z + v.w * v.w;
#pragma unroll
      for (int off = 1; off < 32; off <<= 1) {
        s += __shfl_xor(s, off); ss += __shfl_xor(ss, off);
      }
      float mu = s * (1.0f / 128.0f);
      float var = ss * (1.0f / 128.0f) - mu * mu;
      float rs = rsqrtf(var + 1e-5f);
      ushort4 lv;
      lv.x = f2b((v.x - mu) * rs * gv.x + bv.x);
      lv.y = f2b((v.y - mu) * rs * gv.y + bv.y);
      lv.z = f2b((v.z - mu) * rs * gv.z + bv.z);
      lv.w = f2b((v.w - mu) * rs * gv.w + bv.w);
      *(ushort4*)(lng + base) = lv;
    }
    if (pass == 0) __syncthreads();   // pout reused by pass 1
  }
}

// ---------------- K5: MLP1(gelu) + MLP2 + residual, 64 tokens/block (r11, unchanged) ----
__global__ __launch_bounds__(256) void mlp_kernel(
    const unsigned short* __restrict__ w1_t, const unsigned short* __restrict__ w2_t,
    const float* __restrict__ par, const void* __restrict__ x,
    const unsigned short* __restrict__ lng, void* __restrict__ out) {
  __shared__ __align__(16) unsigned short hbuf[64 * 264];  // 33792 B; pout overlays
  const int f32 = detect_f32((const uint32_t*)x, threadIdx.x & 63);
  const int tid = threadIdx.x, wave = tid >> 6, lane = tid & 63;
  const int quad = lane >> 4, lcol = lane & 15;
  const int m0 = blockIdx.x * 64;
  const int nb = wave * 16 + lcol;

  bf16x8 a1[4][4];
#pragma unroll
  for (int mt = 0; mt < 4; ++mt)
#pragma unroll
    for (int ks = 0; ks < 4; ++ks)
      a1[mt][ks] = *(const bf16x8*)(lng + (size_t)(m0 + mt * 16 + lcol) * 128 +
                                    ks * 32 + quad * 8);

  f32x4 acc2[2][4];
#pragma unroll
  for (int a = 0; a < 2; ++a)
#pragma unroll
    for (int b = 0; b < 4; ++b) acc2[a][b] = (f32x4){0.f, 0.f, 0.f, 0.f};

#pragma unroll 1
  for (int g = 0; g < 2; ++g) {
    for (int p = 0; p < 4; ++p) {
      const int nl = p * 64 + nb;
      const int n = g * 256 + nl;
      bf16x8 bfr[4];
#pragma unroll
      for (int ks = 0; ks < 4; ++ks)
        bfr[ks] = *(const bf16x8*)(w1_t + (size_t)n * 128 + ks * 32 + quad * 8);
      const float bc = par[P_B1 + n];
#pragma unroll
      for (int mt = 0; mt < 4; ++mt) {
        f32x4 acc = (f32x4){0.f, 0.f, 0.f, 0.f};
#pragma unroll
        for (int ks = 0; ks < 4; ++ks)
          acc = __builtin_amdgcn_mfma_f32_16x16x32_bf16(a1[mt][ks], bfr[ks], acc, 0, 0, 0);
#pragma unroll
        for (int rr = 0; rr < 4; ++rr) {
          int m = mt * 16 + quad * 4 + rr;
          hbuf[m * 264 + nl] = f2b(gelu_f(acc[rr] + bc));
        }
      }
    }
    __syncthreads();

#pragma unroll
    for (int np = 0; np < 2; ++np) {
      for (int kp = 0; kp < 2; ++kp) {
        bf16x8 b2r[4];
#pragma unroll
        for (int ks = 0; ks < 4; ++ks)
          b2r[ks] = *(const bf16x8*)(w2_t + (size_t)(np * 64 + nb) * 512 + g * 256 +
                                     kp * 128 + ks * 32 + quad * 8);
#pragma unroll
        for (int mt = 0; mt < 4; ++mt) {
#pragma unroll
          for (int ks = 0; ks < 4; ++ks) {
            bf16x8 a = *(const bf16x8*)(hbuf + (mt * 16 + lcol) * 264 + kp * 128 +
                                        ks * 32 + quad * 8);
            acc2[np][mt] = __builtin_amdgcn_mfma_f32_16x16x32_bf16(a, b2r[ks], acc2[np][mt], 0, 0, 0);
          }
        }
      }
    }
    __syncthreads();
  }

  float* pout = (float*)hbuf;
#pragma unroll
  for (int np = 0; np < 2; ++np) {
    const int n = np * 64 + nb;
    const float bc = par[P_B2 + n];
#pragma unroll
    for (int mt = 0; mt < 4; ++mt)
#pragma unroll
      for (int rr = 0; rr < 4; ++rr)
        pout[(mt * 16 + quad * 4 + rr) * 132 + n] = acc2[np][mt][rr] + bc;
  }
  __syncthreads();

  for (int i = tid; i < 2048; i += 256) {
    int t = i >> 5, c = (i & 31) * 4;
    size_t base = (size_t)(m0 + t) * 128 + c;
    float4 p = *(const float4*)(pout + t * 132 + c);
    if (f32) {
      const float4 xr = *(const float4*)((const float*)out + base);
      float4 ov = make_float4(p.x + xr.x, p.y + xr.y, p.z + xr.z, p.w + xr.w);
      *(float4*)((float*)out + base) = ov;
    } else {
      const ushort4 xr = *(const ushort4*)((const unsigned short*)out + base);
      ushort4 ov;
      ov.x = f2b(p.x + b2f(xr.x)); ov.y = f2b(p.y + b2f(xr.y));
      ov.z = f2b(p.z + b2f(xr.z)); ov.w = f2b(p.w + b2f(xr.w));
      *(ushort4*)((unsigned short*)out + base) = ov;
    }
  }
}

// ---------------- host launch ----------------
extern "C" void kernel_launch(void* const* d_in, const int* in_sizes, int n_in,
                              void* d_out, int out_size, void* d_ws, size_t ws_size,
                              hipStream_t stream) {
  const void* x      = d_in[0];
  const int*  rel    = (const int*)d_in[1];
  const void* rpb    = d_in[2];
  const void* qkv_w  = d_in[3];
  const void* qkv_b  = d_in[4];
  const void* proj_w = d_in[5];
  const void* proj_b = d_in[6];
  const void* ln1_g  = d_in[7];
  const void* ln1_b  = d_in[8];
  const void* ln2_g  = d_in[9];
  const void* ln2_b  = d_in[10];
  const void* w1     = d_in[11];
  const void* b1     = d_in[12];
  const void* w2     = d_in[13];
  const void* b2     = d_in[14];

  char* ws = (char*)d_ws;
  float*          bias_t = (float*)(ws + BIAST_OFF);
  unsigned short* kg   = (unsigned short*)(ws + KG_OFF);
  unsigned short* vgt  = (unsigned short*)(ws + VGT_OFF);
  unsigned short* zpad = (unsigned short*)(ws + ZPAD_OFF);
  unsigned short* wq_t = (unsigned short*)(ws + WQ_OFF);
  unsigned short* wp_t = (unsigned short*)(ws + WP_OFF);
  unsigned short* w1_t = (unsigned short*)(ws + W1_OFF);
  unsigned short* w2_t = (unsigned short*)(ws + W2_OFF);
  float*          par  = (float*)(ws + PAR_OFF);
  unsigned short* lng  = (unsigned short*)(ws + LNG_OFF);

  prep_kernel<<<791 + 196, 256, 0, stream>>>(
      (const uint32_t*)x, qkv_w, proj_w, w1, w2, ln1_g, ln1_b, ln2_g, ln2_b,
      qkv_b, proj_b, b1, b2, rel, rpb,
      wq_t, wp_t, w1_t, w2_t, par, zpad, bias_t);
  attn_fused_kernel<<<NWIN, 256, 0, stream>>>(x, wq_t, bias_t, wp_t, par,
                                              kg, vgt, lng, d_out);
  mlp_kernel<<<100352 / 64, 256, 0, stream>>>(w1_t, w2_t, par, x, lng, d_out);
}

// Round 14
// 361.205 us; speedup vs baseline: 1.1801x; 1.0059x over previous
//
#include <hip/hip_runtime.h>
#include <hip/hip_bf16.h>
#include <cstdint>

#define NWIN   1024
#define NTOK   98
#define BIAS_N 9604   // 98*98

typedef __attribute__((ext_vector_type(8))) short bf16x8;
typedef __attribute__((ext_vector_type(4))) float f32x4;

__device__ __forceinline__ float b2f(unsigned short u) {
  union { uint32_t i; float f; } v; v.i = ((uint32_t)u) << 16; return v.f;
}
__device__ __forceinline__ float b2f_lo(uint32_t u) {
  union { uint32_t i; float f; } v; v.i = u << 16; return v.f;
}
__device__ __forceinline__ float b2f_hi(uint32_t u) {
  union { uint32_t i; float f; } v; v.i = u & 0xffff0000u; return v.f;
}
__device__ __forceinline__ unsigned short f2b(float f) {  // RNE
  union { float f; uint32_t i; } v; v.f = f;
  uint32_t r = v.i + 0x7fffu + ((v.i >> 16) & 1u);
  return (unsigned short)(r >> 16);
}
__device__ __forceinline__ float ldf(const void* p, size_t i, int f32) {
  return f32 ? ((const float*)p)[i] : b2f(((const unsigned short*)p)[i]);
}
__device__ __forceinline__ float2 ldf2(const void* p, size_t i, int f32) {  // i even
  if (f32) { const float* q = (const float*)p + i; return make_float2(q[0], q[1]); }
  uint32_t u = *(const uint32_t*)((const unsigned short*)p + i);
  return make_float2(b2f_lo(u), b2f_hi(u));
}
// per-wave f32-storage detect over x's first 64 dwords (all waves identical)
__device__ __forceinline__ int detect_f32(const uint32_t* __restrict__ xw, int lane) {
  uint32_t w = xw[lane];
  int e = (w >> 23) & 0xFF;
  unsigned long long m = __ballot(e >= 112 && e <= 134);
  return __popcll(m) >= 32;
}
// gelu via A&S 7.1.26 erf (max abs err 1.5e-7; branch-free, hw rcp+exp)
__device__ __forceinline__ float gelu_f(float x) {
  float a = fabsf(x) * 0.70710678118654752f;
  float t = __builtin_amdgcn_rcpf(1.0f + 0.3275911f * a);
  float p = ((((1.061405429f * t - 1.453152027f) * t + 1.421413741f) * t
              - 0.284496736f) * t + 0.254829592f) * t;
  float erfp = 1.0f - p * __expf(-a * a);
  return 0.5f * x * (1.0f + copysignf(erfp, x));
}

// ws offsets (bytes)
#define BIAST_OFF 0          // f32 [4][112][112] transposed bias (in dead QG region)
#define KG_OFF   25690112    // bf16 [1024][4][98][32] K (written+read by fused kernel)
#define VGT_OFF  51380224    // bf16 [1024][4][32][112] transposed V
#define ZPAD_OFF 80740352    // 8192 B zeros (guards V-frag over-reads at region end)
#define WQ_OFF   80902208    // bf16 [384][128]
#define WP_OFF   81000512    // bf16 [128][128]
#define W1_OFF   81033280    // bf16 [512][128]
#define W2_OFF   81164352    // bf16 [128][512]
#define PAR_OFF  81295424    // f32 x 1664
#define LNG_OFF  81302144    // bf16 [100352][128] LN2'd tokens (written by fused K4)
// param layout (float idx)
#define P_LN1G 0
#define P_LN1B 128
#define P_LN2G 256
#define P_LN2B 384
#define P_QKVB 512
#define P_PROJB 896
#define P_B1  1024
#define P_B2  1536

// ---------------- K1: weights + params + zpad + transposed bias, detect inlined ---------
__global__ __launch_bounds__(256) void prep_kernel(
    const uint32_t* __restrict__ xw,
    const void* __restrict__ qkvw, const void* __restrict__ projw,
    const void* __restrict__ w1, const void* __restrict__ w2,
    const void* __restrict__ ln1g, const void* __restrict__ ln1b,
    const void* __restrict__ ln2g, const void* __restrict__ ln2b,
    const void* __restrict__ qkvb, const void* __restrict__ projb,
    const void* __restrict__ b1, const void* __restrict__ b2,
    const int* __restrict__ rel_idx, const void* __restrict__ tbl,
    unsigned short* __restrict__ wq_t, unsigned short* __restrict__ wp_t,
    unsigned short* __restrict__ w1_t, unsigned short* __restrict__ w2_t,
    float* __restrict__ par, unsigned short* __restrict__ zpad,
    float* __restrict__ bias_t) {
  const int f32 = detect_f32(xw, threadIdx.x & 63);
  const int bid = blockIdx.x;
  if (bid < 791) {
    int idx = bid * 256 + threadIdx.x;
    if (idx < 49152) {
      int n = idx >> 7, k = idx & 127;
      wq_t[idx] = f2b(ldf(qkvw, (size_t)k * 384 + n, f32));
    } else if ((idx -= 49152) < 16384) {
      int n = idx >> 7, k = idx & 127;
      wp_t[idx] = f2b(ldf(projw, (size_t)k * 128 + n, f32));
    } else if ((idx -= 16384) < 65536) {
      int n = idx >> 7, k = idx & 127;
      w1_t[idx] = f2b(ldf(w1, (size_t)k * 512 + n, f32));
    } else if ((idx -= 65536) < 65536) {
      int n = idx >> 9, k = idx & 511;
      w2_t[idx] = f2b(ldf(w2, (size_t)k * 128 + n, f32));
    } else if ((idx -= 65536) < 1664) {
      float v;
      if      (idx < 128)  v = ldf(ln1g, idx, f32);
      else if (idx < 256)  v = ldf(ln1b, idx - 128, f32);
      else if (idx < 384)  v = ldf(ln2g, idx - 256, f32);
      else if (idx < 512)  v = ldf(ln2b, idx - 384, f32);
      else if (idx < 896)  v = ldf(qkvb, idx - 512, f32);
      else if (idx < 1024) v = ldf(projb, idx - 896, f32);
      else if (idx < 1536) v = ldf(b1, idx - 1024, f32);
      else                 v = ldf(b2, idx - 1536, f32);
      par[idx] = v;
    } else if ((idx -= 1664) < 4096) {
      zpad[idx] = 0;
    }
  } else {
    // bias_t[h][j][i] (i is fast dim, padded to 112) = tbl[rel_idx[i*98+j]][h]
    int t = (bid - 791) * 256 + threadIdx.x;
    if (t < 4 * 112 * 112) {
      int h = t / 12544, rem = t % 12544, j = rem / 112, i = rem % 112;
      float v = 0.f;
      if (i < NTOK && j < NTOK) v = ldf(tbl, (size_t)rel_idx[i * NTOK + j] * 4 + h, f32);
      bias_t[t] = v;
    }
  }
}

// ---------------- K4: FUSED LN1+QKV+attention+proj+residual+LN2, 1 block/window ----------
// r13 changes vs r12 (phase C only):
// (a) V B-frags hoisted to registers ONCE (vb[2][4], +32 VGPR) — removes 48 redundant
//     L2 round-trips from the per-mt critical chain; PV is now pure plh-ds_read + MFMA.
// (b) s_setprio(1) around QK and PV MFMA clusters (T5): phases B/C are wave-independent
//     since r12 (role diversity), the regime where setprio measured +4-7% on attn.
__global__ __launch_bounds__(256, 3) void attn_fused_kernel(
    const void* __restrict__ x,
    const unsigned short* __restrict__ wq_t, const float* __restrict__ bias_t,
    const unsigned short* __restrict__ wp_t, const float* __restrict__ par,
    unsigned short* __restrict__ kg, unsigned short* __restrict__ vgt,
    unsigned short* __restrict__ lng, void* __restrict__ out) {
  __shared__ __align__(16) unsigned short smem[25872];   // 51744 B
  const int f32 = detect_f32((const uint32_t*)x, threadIdx.x & 63);
  const int tid = threadIdx.x, wave = tid >> 6, lane = tid & 63;
  const int quad = lane >> 4, lcol = lane & 15;
  const int win = blockIdx.x, h = wave;
  const int bb = win >> 8, rW = win & 255;
  const int wd = rW >> 6, r2 = rW & 63, wh = r2 >> 3, ww = r2 & 7;

  unsigned short* lnx = smem;            // [98][136]
  unsigned short* qs  = smem + 13328;    // [4][98][32] wave-private slices

  // ---- Phase A: LN1 + gather -> lnx ----
  for (int t = wave; t < NTOK; t += 4) {
    int td = t / 49, r3 = t % 49, th = r3 / 7, tw = r3 % 7;
    int sd = (wd * 2 + td + 1) & 7;
    int sh = (wh * 7 + th + 3) % 56;
    int sw = (ww * 7 + tw + 3) % 56;
    size_t src = ((((size_t)bb * 8 + sd) * 56 + sh) * 56 + sw) * 128;
    int c0 = lane * 2;
    float2 f = ldf2(x, src + c0, f32);
    float s = f.x + f.y, ss = f.x * f.x + f.y * f.y;
#pragma unroll
    for (int off = 32; off >= 1; off >>= 1) { s += __shfl_xor(s, off); ss += __shfl_xor(ss, off); }
    float mu = s * (1.0f / 128.0f);
    float var = ss * (1.0f / 128.0f) - mu * mu;
    float rs = rsqrtf(var + 1e-5f);
    float y0 = (f.x - mu) * rs * par[P_LN1G + c0] + par[P_LN1B + c0];
    float y1 = (f.y - mu) * rs * par[P_LN1G + c0 + 1] + par[P_LN1B + c0 + 1];
    *(uint32_t*)(lnx + t * 136 + c0) = (uint32_t)f2b(y0) | ((uint32_t)f2b(y1) << 16);
  }
  __syncthreads();   // lnx complete (read by all waves in B)

  // ---- Phase B: QKV MFMA, head h = wave (wave-private outputs) ----
  for (int p = 0; p < 6; ++p) {
    const int region = p >> 1;                      // 0=Q 1=K 2=V
    const int d = (p & 1) * 16 + lcol;              // d in [0,32)
    const int n = region * 128 + h * 32 + d;
    bf16x8 bfr[4];
#pragma unroll
    for (int ks4 = 0; ks4 < 4; ++ks4)
      bfr[ks4] = *(const bf16x8*)(wq_t + (size_t)n * 128 + ks4 * 32 + quad * 8);
    const float bc = par[P_QKVB + n];
    if (region == 0) {
      unsigned short* dstl = qs + h * 3136 + d;
      for (int mt = 0; mt < 7; ++mt) {
        f32x4 acc = (f32x4){0.f, 0.f, 0.f, 0.f};
#pragma unroll
        for (int ks4 = 0; ks4 < 4; ++ks4) {
          bf16x8 a = *(const bf16x8*)(lnx + min(mt * 16 + lcol, NTOK - 1) * 136 +
                                      ks4 * 32 + quad * 8);
          acc = __builtin_amdgcn_mfma_f32_16x16x32_bf16(a, bfr[ks4], acc, 0, 0, 0);
        }
#pragma unroll
        for (int rr = 0; rr < 4; ++rr) {
          int m = mt * 16 + quad * 4 + rr;
          if (m < NTOK) dstl[m * 32] = f2b((acc[rr] + bc) * 0.17677669529663687f);
        }
      }
    } else if (region == 1) {
      unsigned short* dstg = kg + ((size_t)win * 4 + h) * 3136 + d;
      for (int mt = 0; mt < 7; ++mt) {
        f32x4 acc = (f32x4){0.f, 0.f, 0.f, 0.f};
#pragma unroll
        for (int ks4 = 0; ks4 < 4; ++ks4) {
          bf16x8 a = *(const bf16x8*)(lnx + min(mt * 16 + lcol, NTOK - 1) * 136 +
                                      ks4 * 32 + quad * 8);
          acc = __builtin_amdgcn_mfma_f32_16x16x32_bf16(a, bfr[ks4], acc, 0, 0, 0);
        }
#pragma unroll
        for (int rr = 0; rr < 4; ++rr) {
          int m = mt * 16 + quad * 4 + rr;
          if (m < NTOK) dstg[m * 32] = f2b(acc[rr] + bc);
        }
      }
    } else {
      unsigned short* dstv = vgt + (((size_t)win * 4 + h) * 32 + d) * 112;
      for (int mt = 0; mt < 7; ++mt) {
        f32x4 acc = (f32x4){0.f, 0.f, 0.f, 0.f};
#pragma unroll
        for (int ks4 = 0; ks4 < 4; ++ks4) {
          bf16x8 a = *(const bf16x8*)(lnx + min(mt * 16 + lcol, NTOK - 1) * 136 +
                                      ks4 * 32 + quad * 8);
          acc = __builtin_amdgcn_mfma_f32_16x16x32_bf16(a, bfr[ks4], acc, 0, 0, 0);
        }
        ushort4 w;
        int m0 = mt * 16 + quad * 4;
        w.x = (m0 + 0 < NTOK) ? f2b(acc[0] + bc) : (unsigned short)0;
        w.y = (m0 + 1 < NTOK) ? f2b(acc[1] + bc) : (unsigned short)0;
        w.z = (m0 + 2 < NTOK) ? f2b(acc[2] + bc) : (unsigned short)0;
        w.w = (m0 + 3 < NTOK) ? f2b(acc[3] + bc) : (unsigned short)0;
        *(ushort4*)(dstv + m0) = w;
      }
    }
  }
  // NO barrier: qs/kg/vgt are wave-private. Drain own global stores before C reads.
  asm volatile("s_waitcnt vmcnt(0)" ::: "memory");

  // ---- Phase C: attention for head h = wave ----
  const size_t hb = ((size_t)win * 4 + h) * 3136;
  const unsigned short* vbase = vgt + (((size_t)win * 4 + h) * 32) * 112;

  // consume own qs into regs, then overlay plh onto own qs slice (in-wave ds order)
  bf16x8 aq[7], bk[7];
#pragma unroll
  for (int t = 0; t < 7; ++t) {
    int row = min(t * 16 + lcol, NTOK - 1);
    aq[t] = *(const bf16x8*)(qs + h * 3136 + row * 32 + quad * 8);
    bk[t] = *(const bf16x8*)(kg + hb + (size_t)row * 32 + quad * 8);
  }
  // V B-frags hoisted once (reused across all 7 mt iterations)
  bf16x8 vb[2][4];
#pragma unroll
  for (int n2 = 0; n2 < 2; ++n2)
#pragma unroll
    for (int kp = 0; kp < 4; ++kp)
      vb[n2][kp] = *(const bf16x8*)(vbase + (size_t)(n2 * 16 + lcol) * 112 +
                                    kp * 32 + quad * 8);
  unsigned short* plh = qs + h * 3136;   // [16][132] overlays own dead qs slice
  for (int idx = lane; idx < 16 * 16; idx += 64) {
    int rr = idx >> 4, c = 112 + (idx & 15);
    plh[rr * 132 + c] = 0;
  }

  const float* bh = bias_t + h * 12544;   // [112][112], [j][i]
  f32x4 o[7][2];
  for (int mt = 0; mt < 7; ++mt) {
    f32x4 s[7];
    __builtin_amdgcn_s_setprio(1);
#pragma unroll
    for (int nt = 0; nt < 7; ++nt)
      s[nt] = __builtin_amdgcn_mfma_f32_16x16x32_bf16(aq[mt], bk[nt],
                                                      (f32x4){0.f, 0.f, 0.f, 0.f}, 0, 0, 0);
    __builtin_amdgcn_s_setprio(0);
    const int ib = mt * 16 + quad * 4;
#pragma unroll
    for (int nt = 0; nt < 7; ++nt) {
      int j = nt * 16 + lcol;
      bool jv = j < NTOK;
      const float4 bv4 = *(const float4*)(bh + j * 112 + ib);
      s[nt][0] = jv ? (s[nt][0] + bv4.x) : -3.0e38f;
      s[nt][1] = jv ? (s[nt][1] + bv4.y) : -3.0e38f;
      s[nt][2] = jv ? (s[nt][2] + bv4.z) : -3.0e38f;
      s[nt][3] = jv ? (s[nt][3] + bv4.w) : -3.0e38f;
    }
    float mx[4], sum[4], inv[4];
#pragma unroll
    for (int r = 0; r < 4; ++r) {
      float m = s[0][r];
#pragma unroll
      for (int nt = 1; nt < 7; ++nt) m = fmaxf(m, s[nt][r]);
      mx[r] = m;
    }
#pragma unroll
    for (int off = 1; off < 16; off <<= 1)
#pragma unroll
      for (int r = 0; r < 4; ++r) mx[r] = fmaxf(mx[r], __shfl_xor(mx[r], off));
#pragma unroll
    for (int r = 0; r < 4; ++r) sum[r] = 0.f;
#pragma unroll
    for (int nt = 0; nt < 7; ++nt)
#pragma unroll
      for (int r = 0; r < 4; ++r) {
        float e = __expf(s[nt][r] - mx[r]);
        s[nt][r] = e; sum[r] += e;
      }
#pragma unroll
    for (int off = 1; off < 16; off <<= 1)
#pragma unroll
      for (int r = 0; r < 4; ++r) sum[r] += __shfl_xor(sum[r], off);
#pragma unroll
    for (int r = 0; r < 4; ++r) inv[r] = 1.0f / sum[r];
#pragma unroll
    for (int nt = 0; nt < 7; ++nt)
#pragma unroll
      for (int r = 0; r < 4; ++r)
        plh[(quad * 4 + r) * 132 + nt * 16 + lcol] = f2b(s[nt][r] * inv[r]);
    // PV: A = P tile (K padded, from own-wave LDS), B = vb regs
    __builtin_amdgcn_s_setprio(1);
#pragma unroll
    for (int n2 = 0; n2 < 2; ++n2) {
      f32x4 acc = (f32x4){0.f, 0.f, 0.f, 0.f};
#pragma unroll
      for (int kp = 0; kp < 4; ++kp) {
        bf16x8 a = *(const bf16x8*)(plh + lcol * 132 + kp * 32 + quad * 8);
        acc = __builtin_amdgcn_mfma_f32_16x16x32_bf16(a, vb[n2][kp], acc, 0, 0, 0);
      }
      o[mt][n2] = acc;
    }
    __builtin_amdgcn_s_setprio(0);
  }
  __syncthreads();   // ALL waves done with B (lnx reads) + C (plh) before olds overlay

  // ---- attn-out -> olds[112][136] @0 ----
  unsigned short* olds = smem;
#pragma unroll
  for (int mt = 0; mt < 7; ++mt)
#pragma unroll
    for (int n2 = 0; n2 < 2; ++n2)
#pragma unroll
      for (int r = 0; r < 4; ++r)
        olds[(mt * 16 + quad * 4 + r) * 136 + h * 32 + n2 * 16 + lcol] = f2b(o[mt][n2][r]);
  __syncthreads();

  // ---- proj into registers ----
  f32x4 pr[2][7];
  for (int t2 = 0; t2 < 2; ++t2) {
    const int n = (h * 2 + t2) * 16 + lcol;
    bf16x8 bw[4];
#pragma unroll
    for (int kp = 0; kp < 4; ++kp)
      bw[kp] = *(const bf16x8*)(wp_t + (size_t)n * 128 + kp * 32 + quad * 8);
    for (int mt = 0; mt < 7; ++mt) {
      f32x4 acc = (f32x4){0.f, 0.f, 0.f, 0.f};
#pragma unroll
      for (int kp = 0; kp < 4; ++kp) {
        bf16x8 a = *(const bf16x8*)(olds + (mt * 16 + lcol) * 136 + kp * 32 + quad * 8);
        acc = __builtin_amdgcn_mfma_f32_16x16x32_bf16(a, bw[kp], acc, 0, 0, 0);
      }
      pr[t2][mt] = acc;
    }
  }
  __syncthreads();   // olds dead before pout overlays smem

  // ---- two-pass epilogue: pout[56][132] f32, residual + LN2 + stores ----
  const int c = (tid & 31) * 4;
  const float4 gv = *(const float4*)(par + P_LN2G + c);
  const float4 bv = *(const float4*)(par + P_LN2B + c);
  float* pout = (float*)smem;
  for (int pass = 0; pass < 2; ++pass) {
    const int mlo = pass * 56;
    for (int t2 = 0; t2 < 2; ++t2) {
      const int n = (h * 2 + t2) * 16 + lcol;
      const float bc = par[P_PROJB + n];
#pragma unroll
      for (int mt = 0; mt < 7; ++mt)
#pragma unroll
        for (int r = 0; r < 4; ++r) {
          int m = mt * 16 + quad * 4 + r;
          if (m >= mlo && m < mlo + 56 && m < NTOK)
            pout[(m - mlo) * 132 + n] = pr[t2][mt][r] + bc;
        }
    }
    __syncthreads();
    for (int i = tid >> 5; i < 56; i += 8) {
      int m = mlo + i;
      if (m >= NTOK) break;
      int td = m / 49, r3 = m % 49, th = r3 / 7, tw = r3 % 7;
      int sd = (wd * 2 + td + 1) & 7;
      int sh = (wh * 7 + th + 3) % 56;
      int sw = (ww * 7 + tw + 3) % 56;
      size_t base = ((((size_t)bb * 8 + sd) * 56 + sh) * 56 + sw) * 128 + c;
      float4 p = *(const float4*)(pout + i * 132 + c);
      float4 v;
      if (f32) {
        const float4 xr = *(const float4*)((const float*)x + base);
        v = make_float4(p.x + xr.x, p.y + xr.y, p.z + xr.z, p.w + xr.w);
        *(float4*)((float*)out + base) = v;
      } else {
        const ushort4 xr = *(const ushort4*)((const unsigned short*)x + base);
        v = make_float4(p.x + b2f(xr.x), p.y + b2f(xr.y),
                        p.z + b2f(xr.z), p.w + b2f(xr.w));
        ushort4 ov;
        ov.x = f2b(v.x); ov.y = f2b(v.y); ov.z = f2b(v.z); ov.w = f2b(v.w);
        *(ushort4*)((unsigned short*)out + base) = ov;
      }
      // fused LN2 over the 32-lane row -> lng (bf16)
      float s = v.x + v.y + v.z + v.w;
      float ss = v.x * v.x + v.y * v.y + v.z * v.z + v.w * v.w;
#pragma unroll
      for (int off = 1; off < 32; off <<= 1) {
        s += __shfl_xor(s, off); ss += __shfl_xor(ss, off);
      }
      float mu = s * (1.0f / 128.0f);
      float var = ss * (1.0f / 128.0f) - mu * mu;
      float rs = rsqrtf(var + 1e-5f);
      ushort4 lv;
      lv.x = f2b((v.x - mu) * rs * gv.x + bv.x);
      lv.y = f2b((v.y - mu) * rs * gv.y + bv.y);
      lv.z = f2b((v.z - mu) * rs * gv.z + bv.z);
      lv.w = f2b((v.w - mu) * rs * gv.w + bv.w);
      *(ushort4*)(lng + base) = lv;
    }
    if (pass == 0) __syncthreads();   // pout reused by pass 1
  }
}

// ---------------- K5: MLP1(gelu) + MLP2 + residual, 64 tokens/block (r11, unchanged) ----
__global__ __launch_bounds__(256) void mlp_kernel(
    const unsigned short* __restrict__ w1_t, const unsigned short* __restrict__ w2_t,
    const float* __restrict__ par, const void* __restrict__ x,
    const unsigned short* __restrict__ lng, void* __restrict__ out) {
  __shared__ __align__(16) unsigned short hbuf[64 * 264];  // 33792 B; pout overlays
  const int f32 = detect_f32((const uint32_t*)x, threadIdx.x & 63);
  const int tid = threadIdx.x, wave = tid >> 6, lane = tid & 63;
  const int quad = lane >> 4, lcol = lane & 15;
  const int m0 = blockIdx.x * 64;
  const int nb = wave * 16 + lcol;

  bf16x8 a1[4][4];
#pragma unroll
  for (int mt = 0; mt < 4; ++mt)
#pragma unroll
    for (int ks = 0; ks < 4; ++ks)
      a1[mt][ks] = *(const bf16x8*)(lng + (size_t)(m0 + mt * 16 + lcol) * 128 +
                                    ks * 32 + quad * 8);

  f32x4 acc2[2][4];
#pragma unroll
  for (int a = 0; a < 2; ++a)
#pragma unroll
    for (int b = 0; b < 4; ++b) acc2[a][b] = (f32x4){0.f, 0.f, 0.f, 0.f};

#pragma unroll 1
  for (int g = 0; g < 2; ++g) {
    for (int p = 0; p < 4; ++p) {
      const int nl = p * 64 + nb;
      const int n = g * 256 + nl;
      bf16x8 bfr[4];
#pragma unroll
      for (int ks = 0; ks < 4; ++ks)
        bfr[ks] = *(const bf16x8*)(w1_t + (size_t)n * 128 + ks * 32 + quad * 8);
      const float bc = par[P_B1 + n];
#pragma unroll
      for (int mt = 0; mt < 4; ++mt) {
        f32x4 acc = (f32x4){0.f, 0.f, 0.f, 0.f};
#pragma unroll
        for (int ks = 0; ks < 4; ++ks)
          acc = __builtin_amdgcn_mfma_f32_16x16x32_bf16(a1[mt][ks], bfr[ks], acc, 0, 0, 0);
#pragma unroll
        for (int rr = 0; rr < 4; ++rr) {
          int m = mt * 16 + quad * 4 + rr;
          hbuf[m * 264 + nl] = f2b(gelu_f(acc[rr] + bc));
        }
      }
    }
    __syncthreads();

#pragma unroll
    for (int np = 0; np < 2; ++np) {
      for (int kp = 0; kp < 2; ++kp) {
        bf16x8 b2r[4];
#pragma unroll
        for (int ks = 0; ks < 4; ++ks)
          b2r[ks] = *(const bf16x8*)(w2_t + (size_t)(np * 64 + nb) * 512 + g * 256 +
                                     kp * 128 + ks * 32 + quad * 8);
#pragma unroll
        for (int mt = 0; mt < 4; ++mt) {
#pragma unroll
          for (int ks = 0; ks < 4; ++ks) {
            bf16x8 a = *(const bf16x8*)(hbuf + (mt * 16 + lcol) * 264 + kp * 128 +
                                        ks * 32 + quad * 8);
            acc2[np][mt] = __builtin_amdgcn_mfma_f32_16x16x32_bf16(a, b2r[ks], acc2[np][mt], 0, 0, 0);
          }
        }
      }
    }
    __syncthreads();
  }

  float* pout = (float*)hbuf;
#pragma unroll
  for (int np = 0; np < 2; ++np) {
    const int n = np * 64 + nb;
    const float bc = par[P_B2 + n];
#pragma unroll
    for (int mt = 0; mt < 4; ++mt)
#pragma unroll
      for (int rr = 0; rr < 4; ++rr)
        pout[(mt * 16 + quad * 4 + rr) * 132 + n] = acc2[np][mt][rr] + bc;
  }
  __syncthreads();

  for (int i = tid; i < 2048; i += 256) {
    int t = i >> 5, c = (i & 31) * 4;
    size_t base = (size_t)(m0 + t) * 128 + c;
    float4 p = *(const float4*)(pout + t * 132 + c);
    if (f32) {
      const float4 xr = *(const float4*)((const float*)out + base);
      float4 ov = make_float4(p.x + xr.x, p.y + xr.y, p.z + xr.z, p.w + xr.w);
      *(float4*)((float*)out + base) = ov;
    } else {
      const ushort4 xr = *(const ushort4*)((const unsigned short*)out + base);
      ushort4 ov;
      ov.x = f2b(p.x + b2f(xr.x)); ov.y = f2b(p.y + b2f(xr.y));
      ov.z = f2b(p.z + b2f(xr.z)); ov.w = f2b(p.w + b2f(xr.w));
      *(ushort4*)((unsigned short*)out + base) = ov;
    }
  }
}

// ---------------- host launch ----------------
extern "C" void kernel_launch(void* const* d_in, const int* in_sizes, int n_in,
                              void* d_out, int out_size, void* d_ws, size_t ws_size,
                              hipStream_t stream) {
  const void* x      = d_in[0];
  const int*  rel    = (const int*)d_in[1];
  const void* rpb    = d_in[2];
  const void* qkv_w  = d_in[3];
  const void* qkv_b  = d_in[4];
  const void* proj_w = d_in[5];
  const void* proj_b = d_in[6];
  const void* ln1_g  = d_in[7];
  const void* ln1_b  = d_in[8];
  const void* ln2_g  = d_in[9];
  const void* ln2_b  = d_in[10];
  const void* w1     = d_in[11];
  const void* b1     = d_in[12];
  const void* w2     = d_in[13];
  const void* b2     = d_in[14];

  char* ws = (char*)d_ws;
  float*          bias_t = (float*)(ws + BIAST_OFF);
  unsigned short* kg   = (unsigned short*)(ws + KG_OFF);
  unsigned short* vgt  = (unsigned short*)(ws + VGT_OFF);
  unsigned short* zpad = (unsigned short*)(ws + ZPAD_OFF);
  unsigned short* wq_t = (unsigned short*)(ws + WQ_OFF);
  unsigned short* wp_t = (unsigned short*)(ws + WP_OFF);
  unsigned short* w1_t = (unsigned short*)(ws + W1_OFF);
  unsigned short* w2_t = (unsigned short*)(ws + W2_OFF);
  float*          par  = (float*)(ws + PAR_OFF);
  unsigned short* lng  = (unsigned short*)(ws + LNG_OFF);

  prep_kernel<<<791 + 196, 256, 0, stream>>>(
      (const uint32_t*)x, qkv_w, proj_w, w1, w2, ln1_g, ln1_b, ln2_g, ln2_b,
      qkv_b, proj_b, b1, b2, rel, rpb,
      wq_t, wp_t, w1_t, w2_t, par, zpad, bias_t);
  attn_fused_kernel<<<NWIN, 256, 0, stream>>>(x, wq_t, bias_t, wp_t, par,
                                              kg, vgt, lng, d_out);
  mlp_kernel<<<100352 / 64, 256, 0, stream>>>(w1_t, w2_t, par, x, lng, d_out);
}